// Round 2
// baseline (2497.013 us; speedup 1.0000x reference)
//
#include <hip/hip_runtime.h>
#include <math.h>

#define EPSN 1e-12f

// ===================== pixel-descriptor inverse norms =====================
// qinv[b][7500] over query pixels, sinv[b][2500] over support pixels
__global__ void k_pixel_norms(const float* __restrict__ query,
                              const float* __restrict__ support,
                              float* __restrict__ qinv,
                              float* __restrict__ sinv) {
  int idx = blockIdx.x * 256 + threadIdx.x;
  if (idx < 30000) {
    int b = idx / 7500, r = idx % 7500, q = r / 100, p = r % 100;
    const float* base = query + (size_t)((b * 75 + q) * 640) * 100 + p;
    float acc = 0.f;
    #pragma unroll 4
    for (int c = 0; c < 640; ++c) { float v = base[c * 100]; acc = fmaf(v, v, acc); }
    qinv[idx] = 1.f / (sqrtf(acc) + EPSN);
  } else if (idx < 40000) {
    int j = idx - 30000;
    int b = j / 2500, r = j % 2500, s = r / 100, p = r % 100;
    const float* base = support + (size_t)((b * 25 + s) * 640) * 100 + p;
    float acc = 0.f;
    #pragma unroll 4
    for (int c = 0; c < 640; ++c) { float v = base[c * 100]; acc = fmaf(v, v, acc); }
    sinv[j] = 1.f / (sqrtf(acc) + EPSN);
  }
}

// ===================== global path: GAP + prototypes =====================
// qg[(b*75+q)*640+c], proto[(b*5+n)*640+c]
__global__ void k_qg_proto(const float* __restrict__ query,
                           const float* __restrict__ support,
                           float* __restrict__ qg, float* __restrict__ proto) {
  int idx = blockIdx.x * 256 + threadIdx.x;
  if (idx < 192000) {
    const float* base = query + (size_t)idx * 100;
    float s = 0.f;
    #pragma unroll 4
    for (int p = 0; p < 100; ++p) s += base[p];
    qg[idx] = s / 100.f;
  } else if (idx < 204800) {
    int j = idx - 192000;
    int b = j / 3200, r2 = j % 3200, n = r2 / 640, c = r2 % 640;
    float s = 0.f;
    for (int k = 0; k < 5; ++k) {
      const float* base = support + (size_t)((b * 25 + n * 5 + k) * 640 + c) * 100;
      #pragma unroll 4
      for (int p = 0; p < 100; ++p) s += base[p];
    }
    proto[j] = s / 500.f;
  }
}

__global__ void k_global_d2(const float* __restrict__ qg, const float* __restrict__ proto,
                            float* __restrict__ glog) {
  int w = blockIdx.x * 4 + (threadIdx.x >> 6);
  int lane = threadIdx.x & 63;
  if (w >= 1500) return;
  int r = w / 5, n = w % 5;
  int b = r / 75;
  const float* qrow = qg + (size_t)r * 640;
  const float* prow = proto + (size_t)(b * 5 + n) * 640;
  float s = 0.f;
  for (int c = lane; c < 640; c += 64) { float dd = qrow[c] - prow[c]; s = fmaf(dd, dd, s); }
  #pragma unroll
  for (int off = 32; off >= 1; off >>= 1) s += __shfl_xor(s, off, 64);
  if (lane == 0) glog[w] = -s;
}

// ===================== part path: build SP [b][325][640] =====================
__global__ void k_sp_build(const float* __restrict__ spart, float* __restrict__ SP) {
  int idx = blockIdx.x * 256 + threadIdx.x;
  if (idx >= 832000) return;
  int b = idx / (325 * 640);
  int r = idx % (325 * 640);
  int node = r / 640, c = r % 640;
  int s = node / 13, p = node % 13;
  SP[idx] = spart[(size_t)((b * 25 + s) * 640 + c) * 13 + p];
}

// ===================== QKV GEMM: [325x640]@[640x640] per (b, weight) =====================
__global__ __launch_bounds__(256) void k_gemm_qkv(
    const float* __restrict__ SP, const float* __restrict__ Wq,
    const float* __restrict__ Wk, const float* __restrict__ Wv,
    float* __restrict__ Qb, float* __restrict__ Kb, float* __restrict__ Vb) {
  __shared__ float A_s[16][65];
  __shared__ float B_s[16][64];
  int mt = blockIdx.x, nt = blockIdx.y;
  int b = blockIdx.z / 3, w = blockIdx.z % 3;
  const float* W = (w == 0) ? Wq : ((w == 1) ? Wk : Wv);
  float* outp = ((w == 0) ? Qb : ((w == 1) ? Kb : Vb)) + (size_t)b * 325 * 640;
  const float* A = SP + (size_t)b * 325 * 640;
  int tid = threadIdx.x;
  int tx = tid & 15, ty = tid >> 4;
  int lch = tid & 15, lr = tid >> 4;
  int bcol = tid & 63, bkr = tid >> 6;
  float acc[4][4] = {};
  for (int c0 = 0; c0 < 640; c0 += 16) {
    __syncthreads();
    #pragma unroll
    for (int i = 0; i < 4; ++i) {
      int r = lr + 16 * i;
      int m = mt * 64 + r;
      A_s[lch][r] = (m < 325) ? A[(size_t)m * 640 + c0 + lch] : 0.f;
    }
    #pragma unroll
    for (int i = 0; i < 4; ++i) {
      int kk = bkr * 4 + i;
      B_s[kk][bcol] = W[(size_t)(c0 + kk) * 640 + nt * 64 + bcol];
    }
    __syncthreads();
    #pragma unroll
    for (int kk = 0; kk < 16; ++kk) {
      float av[4], bv[4];
      #pragma unroll
      for (int i = 0; i < 4; ++i) av[i] = A_s[kk][ty + 16 * i];
      #pragma unroll
      for (int j = 0; j < 4; ++j) bv[j] = B_s[kk][tx + 16 * j];
      #pragma unroll
      for (int i = 0; i < 4; ++i)
        #pragma unroll
        for (int j = 0; j < 4; ++j)
          acc[i][j] = fmaf(av[i], bv[j], acc[i][j]);
    }
  }
  #pragma unroll
  for (int i = 0; i < 4; ++i) {
    int m = mt * 64 + ty + 16 * i;
    if (m < 325) {
      #pragma unroll
      for (int j = 0; j < 4; ++j)
        outp[(size_t)m * 640 + nt * 64 + tx + 16 * j] = acc[i][j];
    }
  }
}

// ===================== scores = Q@K^T * 1/sqrt(640) (NT GEMM) =====================
__global__ __launch_bounds__(256) void k_gemm_scores(
    const float* __restrict__ Qb, const float* __restrict__ Kb, float* __restrict__ S) {
  __shared__ float A_s[16][65];
  __shared__ float Bt_s[16][65];
  const float SCALE = 0.03952847075210474f; // 1/sqrt(640)
  int mt = blockIdx.x, nt = blockIdx.y, b = blockIdx.z;
  const float* A = Qb + (size_t)b * 325 * 640;
  const float* Km = Kb + (size_t)b * 325 * 640;
  int tid = threadIdx.x;
  int tx = tid & 15, ty = tid >> 4;
  int lch = tid & 15, lr = tid >> 4;
  float acc[4][4] = {};
  for (int c0 = 0; c0 < 640; c0 += 16) {
    __syncthreads();
    #pragma unroll
    for (int i = 0; i < 4; ++i) {
      int r = lr + 16 * i;
      int m = mt * 64 + r;
      A_s[lch][r] = (m < 325) ? A[(size_t)m * 640 + c0 + lch] : 0.f;
      int m2 = nt * 64 + r;
      Bt_s[lch][r] = (m2 < 325) ? Km[(size_t)m2 * 640 + c0 + lch] : 0.f;
    }
    __syncthreads();
    #pragma unroll
    for (int kk = 0; kk < 16; ++kk) {
      float av[4], bv[4];
      #pragma unroll
      for (int i = 0; i < 4; ++i) av[i] = A_s[kk][ty + 16 * i];
      #pragma unroll
      for (int j = 0; j < 4; ++j) bv[j] = Bt_s[kk][tx + 16 * j];
      #pragma unroll
      for (int i = 0; i < 4; ++i)
        #pragma unroll
        for (int j = 0; j < 4; ++j)
          acc[i][j] = fmaf(av[i], bv[j], acc[i][j]);
    }
  }
  #pragma unroll
  for (int i = 0; i < 4; ++i) {
    int m = mt * 64 + ty + 16 * i;
    if (m >= 325) continue;
    #pragma unroll
    for (int j = 0; j < 4; ++j) {
      int col = nt * 64 + tx + 16 * j;
      if (col < 325) S[(size_t)b * 105625 + (size_t)m * 325 + col] = acc[i][j] * SCALE;
    }
  }
}

// ===================== row softmax over 325 (in place) =====================
__global__ void k_softmax_rows(float* __restrict__ S) {
  int w = blockIdx.x * 4 + (threadIdx.x >> 6);
  int lane = threadIdx.x & 63;
  if (w >= 1300) return;
  float* row = S + (size_t)w * 325;
  float ev[6];
  float mx = -1e30f;
  #pragma unroll
  for (int j = 0; j < 6; ++j) {
    int c = lane + 64 * j;
    float x = (c < 325) ? row[c] : -1e30f;
    ev[j] = x;
    mx = fmaxf(mx, x);
  }
  #pragma unroll
  for (int off = 32; off >= 1; off >>= 1) mx = fmaxf(mx, __shfl_xor(mx, off, 64));
  float sum = 0.f;
  #pragma unroll
  for (int j = 0; j < 6; ++j) {
    int c = lane + 64 * j;
    if (c < 325) { float e = expf(ev[j] - mx); ev[j] = e; sum += e; }
    else ev[j] = 0.f;
  }
  #pragma unroll
  for (int off = 32; off >= 1; off >>= 1) sum += __shfl_xor(sum, off, 64);
  float rinv = 1.f / sum;
  #pragma unroll
  for (int j = 0; j < 6; ++j) {
    int c = lane + 64 * j;
    if (c < 325) row[c] = ev[j] * rinv;
  }
}

// ===================== spo = att@V + SP (NN GEMM, K=325) =====================
__global__ __launch_bounds__(256) void k_gemm_av(
    const float* __restrict__ S, const float* __restrict__ Vb,
    const float* __restrict__ SP, float* __restrict__ spo) {
  __shared__ float A_s[16][65];
  __shared__ float B_s[16][64];
  int mt = blockIdx.x, nt = blockIdx.y, b = blockIdx.z;
  const float* A = S + (size_t)b * 105625;
  const float* Bv = Vb + (size_t)b * 325 * 640;
  int tid = threadIdx.x;
  int tx = tid & 15, ty = tid >> 4;
  int lch = tid & 15, lr = tid >> 4;
  int bcol = tid & 63, bkr = tid >> 6;
  float acc[4][4] = {};
  for (int c0 = 0; c0 < 325; c0 += 16) {
    __syncthreads();
    #pragma unroll
    for (int i = 0; i < 4; ++i) {
      int r = lr + 16 * i;
      int m = mt * 64 + r;
      int kidx = c0 + lch;
      A_s[lch][r] = (m < 325 && kidx < 325) ? A[(size_t)m * 325 + kidx] : 0.f;
    }
    #pragma unroll
    for (int i = 0; i < 4; ++i) {
      int kk = bkr * 4 + i;
      int kidx = c0 + kk;
      B_s[kk][bcol] = (kidx < 325) ? Bv[(size_t)kidx * 640 + nt * 64 + bcol] : 0.f;
    }
    __syncthreads();
    #pragma unroll
    for (int kk = 0; kk < 16; ++kk) {
      float av[4], bv[4];
      #pragma unroll
      for (int i = 0; i < 4; ++i) av[i] = A_s[kk][ty + 16 * i];
      #pragma unroll
      for (int j = 0; j < 4; ++j) bv[j] = B_s[kk][tx + 16 * j];
      #pragma unroll
      for (int i = 0; i < 4; ++i)
        #pragma unroll
        for (int j = 0; j < 4; ++j)
          acc[i][j] = fmaf(av[i], bv[j], acc[i][j]);
    }
  }
  #pragma unroll
  for (int i = 0; i < 4; ++i) {
    int m = mt * 64 + ty + 16 * i;
    if (m >= 325) continue;
    #pragma unroll
    for (int j = 0; j < 4; ++j) {
      size_t idx = (size_t)b * 325 * 640 + (size_t)m * 640 + nt * 64 + tx + 16 * j;
      spo[idx] = acc[i][j] + SP[idx];
    }
  }
}

// ===================== part norms =====================
__global__ void k_spinv(const float* __restrict__ spo, float* __restrict__ spinv) {
  int w = blockIdx.x * 4 + (threadIdx.x >> 6);
  int lane = threadIdx.x & 63;
  if (w >= 1300) return;
  const float* base = spo + (size_t)w * 640;
  float s = 0.f;
  for (int c = lane; c < 640; c += 64) { float v = base[c]; s = fmaf(v, v, s); }
  #pragma unroll
  for (int off = 32; off >= 1; off >>= 1) s += __shfl_xor(s, off, 64);
  if (lane == 0) spinv[w] = 1.f / (sqrtf(s) + EPSN);
}

__global__ void k_qpinv(const float* __restrict__ qpart, float* __restrict__ qpinv) {
  int idx = blockIdx.x * 256 + threadIdx.x;
  if (idx >= 3900) return;
  int b = idx / 975, r = idx % 975, q = r / 13, p = r % 13;
  const float* base = qpart + (size_t)(b * 75 + q) * 8320 + p;
  float s = 0.f;
  #pragma unroll 4
  for (int c = 0; c < 640; ++c) { float v = base[c * 13]; s = fmaf(v, v, s); }
  qpinv[idx] = 1.f / (sqrtf(s) + EPSN);
}

// ===================== part similarity =====================
__global__ __launch_bounds__(256) void k_part_sim(
    const float* __restrict__ qpart, const float* __restrict__ qpinv,
    const float* __restrict__ spo, const float* __restrict__ spinv,
    float* __restrict__ plog) {
  __shared__ float qLDS[13 * 640];
  __shared__ float dmat[13 * 65];
  __shared__ float mx13[13];
  int n = blockIdx.x, q = blockIdx.y, b = blockIdx.z;
  int tid = threadIdx.x;
  size_t qbase = (size_t)(b * 75 + q) * 8320;
  for (int e = tid; e < 8320; e += 256) {
    int c = e / 13, p = e % 13;
    qLDS[p * 640 + c] = qpart[qbase + e] * qpinv[(b * 75 + q) * 13 + p];
  }
  __syncthreads();
  int g = tid >> 4, l = tid & 15;
  for (int pair = g; pair < 845; pair += 16) {
    int qp = pair / 65, scol = pair % 65;
    int k = scol / 13, pp = scol % 13;
    int node = (n * 5 + k) * 13 + pp;
    const float* row = spo + (size_t)(b * 325 + node) * 640;
    float sc = spinv[b * 325 + node];
    float sum = 0.f;
    for (int c = l; c < 640; c += 16) sum = fmaf(qLDS[qp * 640 + c], row[c], sum);
    #pragma unroll
    for (int off = 8; off >= 1; off >>= 1) sum += __shfl_xor(sum, off, 16);
    if (l == 0) dmat[pair] = sum * sc;
  }
  __syncthreads();
  if (tid < 13) {
    float m = -1e30f;
    for (int s2 = 0; s2 < 65; ++s2) m = fmaxf(m, dmat[tid * 65 + s2]);
    mx13[tid] = m;
  }
  __syncthreads();
  if (tid == 0) {
    float s = 0.f;
    for (int i = 0; i < 13; ++i) s += mx13[i];
    plog[(b * 75 + q) * 5 + n] = s;
  }
}

// ===================== pixel GEMM with fused strip-max =====================
// grid: (qtile 0..117, strip 0..3, b*5+n), block 256
__global__ __launch_bounds__(256) void k_pixel_gemm(
    const float* __restrict__ query, const float* __restrict__ support,
    const float* __restrict__ qinv, const float* __restrict__ sinv,
    float* __restrict__ pmax) {
  __shared__ __align__(16) float A_s[16][64];
  __shared__ __align__(16) float B_s[16][128];
  int qt = blockIdx.x;
  int strip = blockIdx.y;
  int z = blockIdx.z;
  int b = z / 5, n = z % 5;
  int tid = threadIdx.x;
  // A staging: 64 query pixels x 16 channels
  int apix = tid & 63;
  int arow = tid >> 6;  // 0..3
  int qpix = qt * 64 + apix;
  size_t aBase = 0; float qscale = 0.f;
  if (qpix < 7500) {
    int qq = qpix / 100, p = qpix % 100;
    aBase = (size_t)((b * 75 + qq) * 640) * 100 + p;
    qscale = qinv[b * 7500 + qpix];
  }
  // B staging: 16 channels x 128 support pixels
  int bsp = tid & 127;
  int brow = tid >> 7;  // 0..1
  int spix = strip * 128 + bsp;
  size_t bBase = 0; float sscale = 0.f;
  if (spix < 500) {
    int k = spix / 100, p = spix % 100;
    bBase = (size_t)((b * 25 + n * 5 + k) * 640) * 100 + p;
    sscale = sinv[b * 2500 + n * 500 + spix];
  }
  int tx = tid & 15, ty = tid >> 4;
  float acc[4][8];
  #pragma unroll
  for (int i = 0; i < 4; ++i)
    #pragma unroll
    for (int j = 0; j < 8; ++j) acc[i][j] = 0.f;

  for (int c0 = 0; c0 < 640; c0 += 16) {
    __syncthreads();
    #pragma unroll
    for (int i = 0; i < 4; ++i) {
      int ch = arow * 4 + i;
      A_s[ch][apix] = query[aBase + (size_t)(c0 + ch) * 100] * qscale;
    }
    #pragma unroll
    for (int i = 0; i < 8; ++i) {
      int ch = brow * 8 + i;
      B_s[ch][bsp] = support[bBase + (size_t)(c0 + ch) * 100] * sscale;
    }
    __syncthreads();
    #pragma unroll
    for (int kk = 0; kk < 16; ++kk) {
      float4 a4 = *(const float4*)&A_s[kk][ty * 4];
      float4 b0 = *(const float4*)&B_s[kk][tx * 8];
      float4 b1 = *(const float4*)&B_s[kk][tx * 8 + 4];
      float av[4] = {a4.x, a4.y, a4.z, a4.w};
      float bv[8] = {b0.x, b0.y, b0.z, b0.w, b1.x, b1.y, b1.z, b1.w};
      #pragma unroll
      for (int i = 0; i < 4; ++i)
        #pragma unroll
        for (int j = 0; j < 8; ++j)
          acc[i][j] = fmaf(av[i], bv[j], acc[i][j]);
    }
  }
  // epilogue: per-row max over valid cols of this strip, reduce across tx
  #pragma unroll
  for (int i = 0; i < 4; ++i) {
    int row = qt * 64 + ty * 4 + i;
    float m = -1e30f;
    #pragma unroll
    for (int j = 0; j < 8; ++j) {
      int col = strip * 128 + tx * 8 + j;
      if (col < 500) m = fmaxf(m, acc[i][j]);
    }
    #pragma unroll
    for (int off = 8; off >= 1; off >>= 1) m = fmaxf(m, __shfl_xor(m, off, 16));
    if (tx == 0 && row < 7500) {
      pmax[((size_t)z * 7500 + row) * 4 + strip] = m;
    }
  }
}

// ===================== pixel reduce: sum over hw of max over strips =====================
__global__ void k_pixel_reduce(const float* __restrict__ pmax, float* __restrict__ pxlog) {
  int t = blockIdx.x * 256 + threadIdx.x;
  if (t >= 1500) return;
  int r = t / 5, n = t % 5;
  int b = r / 75, q = r % 75;
  const float* base = pmax + (size_t)((b * 5 + n) * 7500 + q * 100) * 4;
  float s = 0.f;
  for (int p = 0; p < 100; ++p) {
    float m = fmaxf(fmaxf(base[p * 4], base[p * 4 + 1]), fmaxf(base[p * 4 + 2], base[p * 4 + 3]));
    s += m;
  }
  pxlog[t] = s;
}

// ===================== final combine =====================
__device__ inline void softmax5_add(const float* l, float wgt, float* acc) {
  float m = fmaxf(fmaxf(fmaxf(l[0], l[1]), fmaxf(l[2], l[3])), l[4]);
  float e[5]; float s = 0.f;
  #pragma unroll
  for (int i = 0; i < 5; ++i) { e[i] = expf(l[i] - m); s += e[i]; }
  float r = wgt / s;
  #pragma unroll
  for (int i = 0; i < 5; ++i) acc[i] += e[i] * r;
}

__global__ void k_combine(const float* __restrict__ plog, const float* __restrict__ pxlog,
                          const float* __restrict__ glog, float* __restrict__ out) {
  int t = blockIdx.x * blockDim.x + threadIdx.x;
  if (t >= 300) return;
  float accv[5] = {0.f, 0.f, 0.f, 0.f, 0.f};
  float l[5];
  #pragma unroll
  for (int i = 0; i < 5; ++i) l[i] = plog[t * 5 + i];
  softmax5_add(l, 1.0f, accv);
  #pragma unroll
  for (int i = 0; i < 5; ++i) l[i] = pxlog[t * 5 + i];
  softmax5_add(l, 0.5f, accv);
  #pragma unroll
  for (int i = 0; i < 5; ++i) l[i] = glog[t * 5 + i];
  softmax5_add(l, 0.5f, accv);
  #pragma unroll
  for (int i = 0; i < 5; ++i) out[t * 5 + i] = accv[i];
}

// ===================== launch =====================
extern "C" void kernel_launch(void* const* d_in, const int* in_sizes, int n_in,
                              void* d_out, int out_size, void* d_ws, size_t ws_size,
                              hipStream_t stream) {
  (void)in_sizes; (void)n_in; (void)out_size; (void)ws_size;
  const float* support = (const float*)d_in[0];  // [4,25,640,10,10]
  const float* query   = (const float*)d_in[1];  // [4,75,640,10,10]
  const float* spart   = (const float*)d_in[2];  // [4,25,640,13,1]
  const float* qpart   = (const float*)d_in[3];  // [4,75,640,13,1]
  const float* Wq      = (const float*)d_in[4];  // [640,640]
  const float* Wk      = (const float*)d_in[5];
  const float* Wv      = (const float*)d_in[6];
  float* out = (float*)d_out;                    // [300,5]
  float* ws = (float*)d_ws;

  size_t o = 0;
  float* qinv  = ws + o; o += 30000;
  float* sinv  = ws + o; o += 10000;
  float* qg    = ws + o; o += 192000;
  float* proto = ws + o; o += 12800;
  float* SP    = ws + o; o += 832000;
  float* Qb    = ws + o; o += 832000;
  float* Kb    = ws + o; o += 832000;
  float* Vb    = ws + o; o += 832000;
  float* S     = ws + o; o += 422500;   // 4*325*325
  float* spo   = ws + o; o += 832000;
  float* spinv = ws + o; o += 1300;
  float* qpinv = ws + o; o += 3900;
  float* pmax  = ws + o; o += 600000;   // [b][n][7500][4]
  float* plog  = ws + o; o += 1500;
  float* pxlog = ws + o; o += 1500;
  float* glog  = ws + o; o += 1500;

  k_pixel_norms<<<157, 256, 0, stream>>>(query, support, qinv, sinv);
  k_qg_proto<<<800, 256, 0, stream>>>(query, support, qg, proto);
  k_sp_build<<<3250, 256, 0, stream>>>(spart, SP);
  k_gemm_qkv<<<dim3(6, 10, 12), 256, 0, stream>>>(SP, Wq, Wk, Wv, Qb, Kb, Vb);
  k_gemm_scores<<<dim3(6, 6, 4), 256, 0, stream>>>(Qb, Kb, S);
  k_softmax_rows<<<325, 256, 0, stream>>>(S);
  k_gemm_av<<<dim3(6, 10, 4), 256, 0, stream>>>(S, Vb, SP, spo);
  k_spinv<<<325, 256, 0, stream>>>(spo, spinv);
  k_qpinv<<<16, 256, 0, stream>>>(qpart, qpinv);
  k_part_sim<<<dim3(5, 75, 4), 256, 0, stream>>>(qpart, qpinv, spo, spinv, plog);
  k_global_d2<<<375, 256, 0, stream>>>(qg, proto, glog);
  k_pixel_gemm<<<dim3(118, 4, 20), 256, 0, stream>>>(query, support, qinv, sinv, pmax);
  k_pixel_reduce<<<6, 256, 0, stream>>>(pmax, pxlog);
  k_combine<<<1, 512, 0, stream>>>(plog, pxlog, glog, out);
}

// Round 3
// 1315.616 us; speedup vs baseline: 1.8980x; 1.8980x over previous
//
#include <hip/hip_runtime.h>
#include <hip/hip_bf16.h>
#include <math.h>

#define EPSN 1e-12f

using bf16x8 = __attribute__((ext_vector_type(8))) __bf16;
using f32x4  = __attribute__((ext_vector_type(4))) float;

__device__ __forceinline__ void gload_lds16(const void* g, void* l) {
  __builtin_amdgcn_global_load_lds(
      (const __attribute__((address_space(1))) unsigned int*)g,
      (__attribute__((address_space(3))) unsigned int*)l, 16, 0, 0);
}

// ===================== pixel-descriptor inverse norms =====================
__global__ void k_pixel_norms(const float* __restrict__ query,
                              const float* __restrict__ support,
                              float* __restrict__ qinv,
                              float* __restrict__ sinv) {
  int idx = blockIdx.x * 256 + threadIdx.x;
  if (idx < 30000) {
    int b = idx / 7500, r = idx % 7500, q = r / 100, p = r % 100;
    const float* base = query + (size_t)((b * 75 + q) * 640) * 100 + p;
    float acc = 0.f;
    #pragma unroll 4
    for (int c = 0; c < 640; ++c) { float v = base[c * 100]; acc = fmaf(v, v, acc); }
    qinv[idx] = 1.f / (sqrtf(acc) + EPSN);
  } else if (idx < 40000) {
    int j = idx - 30000;
    int b = j / 2500, r = j % 2500, s = r / 100, p = r % 100;
    const float* base = support + (size_t)((b * 25 + s) * 640) * 100 + p;
    float acc = 0.f;
    #pragma unroll 4
    for (int c = 0; c < 640; ++c) { float v = base[c * 100]; acc = fmaf(v, v, acc); }
    sinv[j] = 1.f / (sqrtf(acc) + EPSN);
  }
}

// ===================== transpose [img][640][100] f32 -> [img*100][640] bf16 =====
// optional fused GAP (mean over 100 pixels) into gap[img*640 + c]
__global__ __launch_bounds__(256) void k_transpose_bf16(
    const float* __restrict__ src, __hip_bfloat16* __restrict__ dst,
    float* __restrict__ gap) {
  __shared__ float tile[64][101];
  int img = blockIdx.x;
  int ct = blockIdx.y;              // channel tile 0..9
  const float* s = src + ((size_t)img * 640 + ct * 64) * 100;
  int t = threadIdx.x;
  #pragma unroll
  for (int i = 0; i < 25; ++i) {
    int j = t + i * 256;
    int c = j / 100, p = j % 100;
    tile[c][p] = s[(size_t)c * 100 + p];
  }
  __syncthreads();
  if (gap != nullptr) {
    int c = t >> 2, part = t & 3;
    float sm = 0.f;
    #pragma unroll
    for (int p = 0; p < 25; ++p) sm += tile[c][part * 25 + p];
    sm += __shfl_xor(sm, 1);
    sm += __shfl_xor(sm, 2);
    if (part == 0) gap[(size_t)img * 640 + ct * 64 + c] = sm * 0.01f;
  }
  __hip_bfloat16* d = dst + (size_t)img * 100 * 640 + ct * 64;
  #pragma unroll
  for (int i = 0; i < 25; ++i) {
    int j = t + i * 256;
    int p = j >> 6, c = j & 63;
    d[(size_t)p * 640 + c] = __float2bfloat16(tile[c][p]);
  }
}

// ===================== proto only =====================
__global__ void k_proto(const float* __restrict__ support, float* __restrict__ proto) {
  int j = blockIdx.x * 256 + threadIdx.x;
  if (j >= 12800) return;
  int b = j / 3200, r2 = j % 3200, n = r2 / 640, c = r2 % 640;
  float s = 0.f;
  for (int k = 0; k < 5; ++k) {
    const float* base = support + (size_t)((b * 25 + n * 5 + k) * 640 + c) * 100;
    #pragma unroll 4
    for (int p = 0; p < 100; ++p) s += base[p];
  }
  proto[j] = s / 500.f;
}

__global__ void k_global_d2(const float* __restrict__ qg, const float* __restrict__ proto,
                            float* __restrict__ glog) {
  int w = blockIdx.x * 4 + (threadIdx.x >> 6);
  int lane = threadIdx.x & 63;
  if (w >= 1500) return;
  int r = w / 5, n = w % 5;
  int b = r / 75;
  const float* qrow = qg + (size_t)r * 640;
  const float* prow = proto + (size_t)(b * 5 + n) * 640;
  float s = 0.f;
  for (int c = lane; c < 640; c += 64) { float dd = qrow[c] - prow[c]; s = fmaf(dd, dd, s); }
  #pragma unroll
  for (int off = 32; off >= 1; off >>= 1) s += __shfl_xor(s, off, 64);
  if (lane == 0) glog[w] = -s;
}

// ===================== part path: build SP [b][325][640] =====================
__global__ void k_sp_build(const float* __restrict__ spart, float* __restrict__ SP) {
  int idx = blockIdx.x * 256 + threadIdx.x;
  if (idx >= 832000) return;
  int b = idx / (325 * 640);
  int r = idx % (325 * 640);
  int node = r / 640, c = r % 640;
  int s = node / 13, p = node % 13;
  SP[idx] = spart[(size_t)((b * 25 + s) * 640 + c) * 13 + p];
}

// ===================== QKV GEMM =====================
__global__ __launch_bounds__(256) void k_gemm_qkv(
    const float* __restrict__ SP, const float* __restrict__ Wq,
    const float* __restrict__ Wk, const float* __restrict__ Wv,
    float* __restrict__ Qb, float* __restrict__ Kb, float* __restrict__ Vb) {
  __shared__ float A_s[16][65];
  __shared__ float B_s[16][64];
  int mt = blockIdx.x, nt = blockIdx.y;
  int b = blockIdx.z / 3, w = blockIdx.z % 3;
  const float* W = (w == 0) ? Wq : ((w == 1) ? Wk : Wv);
  float* outp = ((w == 0) ? Qb : ((w == 1) ? Kb : Vb)) + (size_t)b * 325 * 640;
  const float* A = SP + (size_t)b * 325 * 640;
  int tid = threadIdx.x;
  int tx = tid & 15, ty = tid >> 4;
  int lch = tid & 15, lr = tid >> 4;
  int bcol = tid & 63, bkr = tid >> 6;
  float acc[4][4] = {};
  for (int c0 = 0; c0 < 640; c0 += 16) {
    __syncthreads();
    #pragma unroll
    for (int i = 0; i < 4; ++i) {
      int r = lr + 16 * i;
      int m = mt * 64 + r;
      A_s[lch][r] = (m < 325) ? A[(size_t)m * 640 + c0 + lch] : 0.f;
    }
    #pragma unroll
    for (int i = 0; i < 4; ++i) {
      int kk = bkr * 4 + i;
      B_s[kk][bcol] = W[(size_t)(c0 + kk) * 640 + nt * 64 + bcol];
    }
    __syncthreads();
    #pragma unroll
    for (int kk = 0; kk < 16; ++kk) {
      float av[4], bv[4];
      #pragma unroll
      for (int i = 0; i < 4; ++i) av[i] = A_s[kk][ty + 16 * i];
      #pragma unroll
      for (int j = 0; j < 4; ++j) bv[j] = B_s[kk][tx + 16 * j];
      #pragma unroll
      for (int i = 0; i < 4; ++i)
        #pragma unroll
        for (int j = 0; j < 4; ++j)
          acc[i][j] = fmaf(av[i], bv[j], acc[i][j]);
    }
  }
  #pragma unroll
  for (int i = 0; i < 4; ++i) {
    int m = mt * 64 + ty + 16 * i;
    if (m < 325) {
      #pragma unroll
      for (int j = 0; j < 4; ++j)
        outp[(size_t)m * 640 + nt * 64 + tx + 16 * j] = acc[i][j];
    }
  }
}

// ===================== scores = Q@K^T * 1/sqrt(640) =====================
__global__ __launch_bounds__(256) void k_gemm_scores(
    const float* __restrict__ Qb, const float* __restrict__ Kb, float* __restrict__ S) {
  __shared__ float A_s[16][65];
  __shared__ float Bt_s[16][65];
  const float SCALE = 0.03952847075210474f;
  int mt = blockIdx.x, nt = blockIdx.y, b = blockIdx.z;
  const float* A = Qb + (size_t)b * 325 * 640;
  const float* Km = Kb + (size_t)b * 325 * 640;
  int tid = threadIdx.x;
  int tx = tid & 15, ty = tid >> 4;
  int lch = tid & 15, lr = tid >> 4;
  float acc[4][4] = {};
  for (int c0 = 0; c0 < 640; c0 += 16) {
    __syncthreads();
    #pragma unroll
    for (int i = 0; i < 4; ++i) {
      int r = lr + 16 * i;
      int m = mt * 64 + r;
      A_s[lch][r] = (m < 325) ? A[(size_t)m * 640 + c0 + lch] : 0.f;
      int m2 = nt * 64 + r;
      Bt_s[lch][r] = (m2 < 325) ? Km[(size_t)m2 * 640 + c0 + lch] : 0.f;
    }
    __syncthreads();
    #pragma unroll
    for (int kk = 0; kk < 16; ++kk) {
      float av[4], bv[4];
      #pragma unroll
      for (int i = 0; i < 4; ++i) av[i] = A_s[kk][ty + 16 * i];
      #pragma unroll
      for (int j = 0; j < 4; ++j) bv[j] = Bt_s[kk][tx + 16 * j];
      #pragma unroll
      for (int i = 0; i < 4; ++i)
        #pragma unroll
        for (int j = 0; j < 4; ++j)
          acc[i][j] = fmaf(av[i], bv[j], acc[i][j]);
    }
  }
  #pragma unroll
  for (int i = 0; i < 4; ++i) {
    int m = mt * 64 + ty + 16 * i;
    if (m >= 325) continue;
    #pragma unroll
    for (int j = 0; j < 4; ++j) {
      int col = nt * 64 + tx + 16 * j;
      if (col < 325) S[(size_t)b * 105625 + (size_t)m * 325 + col] = acc[i][j] * SCALE;
    }
  }
}

// ===================== row softmax over 325 =====================
__global__ void k_softmax_rows(float* __restrict__ S) {
  int w = blockIdx.x * 4 + (threadIdx.x >> 6);
  int lane = threadIdx.x & 63;
  if (w >= 1300) return;
  float* row = S + (size_t)w * 325;
  float ev[6];
  float mx = -1e30f;
  #pragma unroll
  for (int j = 0; j < 6; ++j) {
    int c = lane + 64 * j;
    float x = (c < 325) ? row[c] : -1e30f;
    ev[j] = x;
    mx = fmaxf(mx, x);
  }
  #pragma unroll
  for (int off = 32; off >= 1; off >>= 1) mx = fmaxf(mx, __shfl_xor(mx, off, 64));
  float sum = 0.f;
  #pragma unroll
  for (int j = 0; j < 6; ++j) {
    int c = lane + 64 * j;
    if (c < 325) { float e = expf(ev[j] - mx); ev[j] = e; sum += e; }
    else ev[j] = 0.f;
  }
  #pragma unroll
  for (int off = 32; off >= 1; off >>= 1) sum += __shfl_xor(sum, off, 64);
  float rinv = 1.f / sum;
  #pragma unroll
  for (int j = 0; j < 6; ++j) {
    int c = lane + 64 * j;
    if (c < 325) row[c] = ev[j] * rinv;
  }
}

// ===================== spo = att@V + SP =====================
__global__ __launch_bounds__(256) void k_gemm_av(
    const float* __restrict__ S, const float* __restrict__ Vb,
    const float* __restrict__ SP, float* __restrict__ spo) {
  __shared__ float A_s[16][65];
  __shared__ float B_s[16][64];
  int mt = blockIdx.x, nt = blockIdx.y, b = blockIdx.z;
  const float* A = S + (size_t)b * 105625;
  const float* Bv = Vb + (size_t)b * 325 * 640;
  int tid = threadIdx.x;
  int tx = tid & 15, ty = tid >> 4;
  int lch = tid & 15, lr = tid >> 4;
  int bcol = tid & 63, bkr = tid >> 6;
  float acc[4][4] = {};
  for (int c0 = 0; c0 < 325; c0 += 16) {
    __syncthreads();
    #pragma unroll
    for (int i = 0; i < 4; ++i) {
      int r = lr + 16 * i;
      int m = mt * 64 + r;
      int kidx = c0 + lch;
      A_s[lch][r] = (m < 325 && kidx < 325) ? A[(size_t)m * 325 + kidx] : 0.f;
    }
    #pragma unroll
    for (int i = 0; i < 4; ++i) {
      int kk = bkr * 4 + i;
      int kidx = c0 + kk;
      B_s[kk][bcol] = (kidx < 325) ? Bv[(size_t)kidx * 640 + nt * 64 + bcol] : 0.f;
    }
    __syncthreads();
    #pragma unroll
    for (int kk = 0; kk < 16; ++kk) {
      float av[4], bv[4];
      #pragma unroll
      for (int i = 0; i < 4; ++i) av[i] = A_s[kk][ty + 16 * i];
      #pragma unroll
      for (int j = 0; j < 4; ++j) bv[j] = B_s[kk][tx + 16 * j];
      #pragma unroll
      for (int i = 0; i < 4; ++i)
        #pragma unroll
        for (int j = 0; j < 4; ++j)
          acc[i][j] = fmaf(av[i], bv[j], acc[i][j]);
    }
  }
  #pragma unroll
  for (int i = 0; i < 4; ++i) {
    int m = mt * 64 + ty + 16 * i;
    if (m >= 325) continue;
    #pragma unroll
    for (int j = 0; j < 4; ++j) {
      size_t idx = (size_t)b * 325 * 640 + (size_t)m * 640 + nt * 64 + tx + 16 * j;
      spo[idx] = acc[i][j] + SP[idx];
    }
  }
}

// ===================== part norms =====================
__global__ void k_spinv(const float* __restrict__ spo, float* __restrict__ spinv) {
  int w = blockIdx.x * 4 + (threadIdx.x >> 6);
  int lane = threadIdx.x & 63;
  if (w >= 1300) return;
  const float* base = spo + (size_t)w * 640;
  float s = 0.f;
  for (int c = lane; c < 640; c += 64) { float v = base[c]; s = fmaf(v, v, s); }
  #pragma unroll
  for (int off = 32; off >= 1; off >>= 1) s += __shfl_xor(s, off, 64);
  if (lane == 0) spinv[w] = 1.f / (sqrtf(s) + EPSN);
}

__global__ void k_qpinv(const float* __restrict__ qpart, float* __restrict__ qpinv) {
  int idx = blockIdx.x * 256 + threadIdx.x;
  if (idx >= 3900) return;
  int b = idx / 975, r = idx % 975, q = r / 13, p = r % 13;
  const float* base = qpart + (size_t)(b * 75 + q) * 8320 + p;
  float s = 0.f;
  #pragma unroll 4
  for (int c = 0; c < 640; ++c) { float v = base[c * 13]; s = fmaf(v, v, s); }
  qpinv[idx] = 1.f / (sqrtf(s) + EPSN);
}

// ===================== part similarity =====================
__global__ __launch_bounds__(256) void k_part_sim(
    const float* __restrict__ qpart, const float* __restrict__ qpinv,
    const float* __restrict__ spo, const float* __restrict__ spinv,
    float* __restrict__ plog) {
  __shared__ float qLDS[13 * 640];
  __shared__ float dmat[13 * 65];
  __shared__ float mx13[13];
  int n = blockIdx.x, q = blockIdx.y, b = blockIdx.z;
  int tid = threadIdx.x;
  size_t qbase = (size_t)(b * 75 + q) * 8320;
  for (int e = tid; e < 8320; e += 256) {
    int c = e / 13, p = e % 13;
    qLDS[p * 640 + c] = qpart[qbase + e] * qpinv[(b * 75 + q) * 13 + p];
  }
  __syncthreads();
  int g = tid >> 4, l = tid & 15;
  for (int pair = g; pair < 845; pair += 16) {
    int qp = pair / 65, scol = pair % 65;
    int k = scol / 13, pp = scol % 13;
    int node = (n * 5 + k) * 13 + pp;
    const float* row = spo + (size_t)(b * 325 + node) * 640;
    float sc = spinv[b * 325 + node];
    float sum = 0.f;
    for (int c = l; c < 640; c += 16) sum = fmaf(qLDS[qp * 640 + c], row[c], sum);
    #pragma unroll
    for (int off = 8; off >= 1; off >>= 1) sum += __shfl_xor(sum, off, 16);
    if (l == 0) dmat[pair] = sum * sc;
  }
  __syncthreads();
  if (tid < 13) {
    float m = -1e30f;
    for (int s2 = 0; s2 < 65; ++s2) m = fmaxf(m, dmat[tid * 65 + s2]);
    mx13[tid] = m;
  }
  __syncthreads();
  if (tid == 0) {
    float s = 0.f;
    for (int i = 0; i < 13; ++i) s += mx13[i];
    plog[(b * 75 + q) * 5 + n] = s;
  }
}

// ===================== pixel GEMM via bf16 MFMA, fused strip-max ===========
// grid: ( strip*5+n [20], qt [59], b [4] ), block 256 (4 waves)
// C tile 128x128 = Qn[qt*128..][.] x Sn[class n strip..]^T, BK=64
__global__ __launch_bounds__(256) void k_pixel_mfma(
    const __hip_bfloat16* __restrict__ Qn, const __hip_bfloat16* __restrict__ Sn,
    const float* __restrict__ qinv, const float* __restrict__ sinv,
    float* __restrict__ pmax) {
  __shared__ __align__(16) __bf16 ldsA[128 * 64];
  __shared__ __align__(16) __bf16 ldsB[128 * 64];
  int x = blockIdx.x;
  int strip = x / 5, n = x % 5;
  int qt = blockIdx.y;
  int b = blockIdx.z;
  int tid = threadIdx.x;
  int w = tid >> 6, lane = tid & 63;
  int l15 = lane & 15, l4 = lane >> 4;

  const __hip_bfloat16* QnB = Qn + (size_t)b * 7500 * 640;
  const __hip_bfloat16* SnB = Sn + ((size_t)b * 2500 + n * 500) * 640;

  f32x4 acc[2][8];
  #pragma unroll
  for (int i = 0; i < 2; ++i)
    #pragma unroll
    for (int j = 0; j < 8; ++j) acc[i][j] = (f32x4){0.f, 0.f, 0.f, 0.f};

  for (int kt = 0; kt < 10; ++kt) {
    int c0 = kt * 64;
    __syncthreads();
    // stage A: rows w*32..w*32+31, pre-swizzled source so linear LDS dest is swizzled
    #pragma unroll
    for (int j = 0; j < 4; ++j) {
      int ci = w * 256 + j * 64 + lane;
      int row = ci >> 3, kc = ci & 7;
      int srcc = kc ^ (row & 7);
      int qrow = qt * 128 + row; if (qrow > 7499) qrow = 7499;
      const __hip_bfloat16* g = QnB + (size_t)qrow * 640 + c0 + srcc * 8;
      char* l = (char*)ldsA + (w * 256 + j * 64) * 16;
      gload_lds16(g, l);
    }
    // stage B: support-pixel rows (= C cols) strip*128 + [0,128)
    #pragma unroll
    for (int j = 0; j < 4; ++j) {
      int ci = w * 256 + j * 64 + lane;
      int row = ci >> 3, kc = ci & 7;
      int srcc = kc ^ (row & 7);
      int srow = strip * 128 + row; if (srow > 499) srow = 499;
      const __hip_bfloat16* g = SnB + (size_t)srow * 640 + c0 + srcc * 8;
      char* l = (char*)ldsB + (w * 256 + j * 64) * 16;
      gload_lds16(g, l);
    }
    __syncthreads();   // compiler drains vmcnt(0) before barrier
    #pragma unroll
    for (int ks = 0; ks < 2; ++ks) {
      int chunk = ks * 4 + l4;
      bf16x8 af[2];
      #pragma unroll
      for (int mf = 0; mf < 2; ++mf) {
        int row = w * 32 + mf * 16 + l15;
        int off = row * 128 + ((chunk ^ (row & 7)) << 4);
        af[mf] = *(const bf16x8*)((const char*)ldsA + off);
      }
      #pragma unroll
      for (int nf = 0; nf < 8; ++nf) {
        int col = nf * 16 + l15;
        int offb = col * 128 + ((chunk ^ (col & 7)) << 4);
        bf16x8 bv = *(const bf16x8*)((const char*)ldsB + offb);
        #pragma unroll
        for (int mf = 0; mf < 2; ++mf)
          acc[mf][nf] = __builtin_amdgcn_mfma_f32_16x16x32_bf16(af[mf], bv, acc[mf][nf], 0, 0, 0);
      }
    }
  }

  // epilogue: scale by norms, mask cols>=500, max over 128 cols, write pmax
  int z = b * 5 + n;
  float sscale[8]; bool svalid[8];
  #pragma unroll
  for (int nf = 0; nf < 8; ++nf) {
    int scol = strip * 128 + nf * 16 + l15;
    svalid[nf] = scol < 500;
    sscale[nf] = sinv[b * 2500 + n * 500 + (svalid[nf] ? scol : 0)];
  }
  #pragma unroll
  for (int mf = 0; mf < 2; ++mf) {
    #pragma unroll
    for (int r = 0; r < 4; ++r) {
      int row = qt * 128 + w * 32 + mf * 16 + l4 * 4 + r;
      bool rvalid = row < 7500;
      float qs = qinv[b * 7500 + (rvalid ? row : 0)];
      float m = -1e30f;
      #pragma unroll
      for (int nf = 0; nf < 8; ++nf) {
        float v = acc[mf][nf][r] * qs * sscale[nf];
        if (svalid[nf]) m = fmaxf(m, v);
      }
      #pragma unroll
      for (int off = 8; off >= 1; off >>= 1) m = fmaxf(m, __shfl_xor(m, off));
      if (l15 == 0 && rvalid)
        pmax[((size_t)z * 7500 + row) * 4 + strip] = m;
    }
  }
}

// ===================== pixel reduce =====================
__global__ void k_pixel_reduce(const float* __restrict__ pmax, float* __restrict__ pxlog) {
  int t = blockIdx.x * 256 + threadIdx.x;
  if (t >= 1500) return;
  int r = t / 5, n = t % 5;
  int b = r / 75, q = r % 75;
  const float* base = pmax + (size_t)((b * 5 + n) * 7500 + q * 100) * 4;
  float s = 0.f;
  for (int p = 0; p < 100; ++p) {
    float m = fmaxf(fmaxf(base[p * 4], base[p * 4 + 1]), fmaxf(base[p * 4 + 2], base[p * 4 + 3]));
    s += m;
  }
  pxlog[t] = s;
}

// ===================== final combine =====================
__device__ inline void softmax5_add(const float* l, float wgt, float* acc) {
  float m = fmaxf(fmaxf(fmaxf(l[0], l[1]), fmaxf(l[2], l[3])), l[4]);
  float e[5]; float s = 0.f;
  #pragma unroll
  for (int i = 0; i < 5; ++i) { e[i] = expf(l[i] - m); s += e[i]; }
  float r = wgt / s;
  #pragma unroll
  for (int i = 0; i < 5; ++i) acc[i] += e[i] * r;
}

__global__ void k_combine(const float* __restrict__ plog, const float* __restrict__ pxlog,
                          const float* __restrict__ glog, float* __restrict__ out) {
  int t = blockIdx.x * blockDim.x + threadIdx.x;
  if (t >= 300) return;
  float accv[5] = {0.f, 0.f, 0.f, 0.f, 0.f};
  float l[5];
  #pragma unroll
  for (int i = 0; i < 5; ++i) l[i] = plog[t * 5 + i];
  softmax5_add(l, 1.0f, accv);
  #pragma unroll
  for (int i = 0; i < 5; ++i) l[i] = pxlog[t * 5 + i];
  softmax5_add(l, 0.5f, accv);
  #pragma unroll
  for (int i = 0; i < 5; ++i) l[i] = glog[t * 5 + i];
  softmax5_add(l, 0.5f, accv);
  #pragma unroll
  for (int i = 0; i < 5; ++i) out[t * 5 + i] = accv[i];
}

// ===================== launch =====================
extern "C" void kernel_launch(void* const* d_in, const int* in_sizes, int n_in,
                              void* d_out, int out_size, void* d_ws, size_t ws_size,
                              hipStream_t stream) {
  (void)in_sizes; (void)n_in; (void)out_size; (void)ws_size;
  const float* support = (const float*)d_in[0];  // [4,25,640,10,10]
  const float* query   = (const float*)d_in[1];  // [4,75,640,10,10]
  const float* spart   = (const float*)d_in[2];  // [4,25,640,13,1]
  const float* qpart   = (const float*)d_in[3];  // [4,75,640,13,1]
  const float* Wq      = (const float*)d_in[4];
  const float* Wk      = (const float*)d_in[5];
  const float* Wv      = (const float*)d_in[6];
  float* out = (float*)d_out;                    // [300,5]
  float* ws = (float*)d_ws;

  size_t o = 0;
  __hip_bfloat16* Qn = (__hip_bfloat16*)(ws + o); o += 9600000;  // 4*7500*640 bf16
  __hip_bfloat16* Sn = (__hip_bfloat16*)(ws + o); o += 3200000;  // 4*2500*640 bf16
  float* qinv  = ws + o; o += 30000;
  float* sinv  = ws + o; o += 10000;
  float* qg    = ws + o; o += 192000;
  float* proto = ws + o; o += 12800;
  float* SP    = ws + o; o += 832000;
  float* Qb    = ws + o; o += 832000;
  float* Kb    = ws + o; o += 832000;
  float* Vb    = ws + o; o += 832000;
  float* S     = ws + o; o += 422500;
  float* spo   = ws + o; o += 832000;
  float* spinv = ws + o; o += 1300;
  float* qpinv = ws + o; o += 3900;
  float* pmax  = ws + o; o += 600000;
  float* plog  = ws + o; o += 1500;
  float* pxlog = ws + o; o += 1500;
  float* glog  = ws + o; o += 1500;

  k_pixel_norms<<<157, 256, 0, stream>>>(query, support, qinv, sinv);
  k_transpose_bf16<<<dim3(300, 10), 256, 0, stream>>>(query, Qn, qg);
  k_transpose_bf16<<<dim3(100, 10), 256, 0, stream>>>(support, Sn, nullptr);
  k_proto<<<50, 256, 0, stream>>>(support, proto);
  k_sp_build<<<3250, 256, 0, stream>>>(spart, SP);
  k_gemm_qkv<<<dim3(6, 10, 12), 256, 0, stream>>>(SP, Wq, Wk, Wv, Qb, Kb, Vb);
  k_gemm_scores<<<dim3(6, 6, 4), 256, 0, stream>>>(Qb, Kb, S);
  k_softmax_rows<<<325, 256, 0, stream>>>(S);
  k_gemm_av<<<dim3(6, 10, 4), 256, 0, stream>>>(S, Vb, SP, spo);
  k_spinv<<<325, 256, 0, stream>>>(spo, spinv);
  k_qpinv<<<16, 256, 0, stream>>>(qpart, qpinv);
  k_part_sim<<<dim3(5, 75, 4), 256, 0, stream>>>(qpart, qpinv, spo, spinv, plog);
  k_global_d2<<<375, 256, 0, stream>>>(qg, proto, glog);
  k_pixel_mfma<<<dim3(20, 59, 4), 256, 0, stream>>>(Qn, Sn, qinv, sinv, pmax);
  k_pixel_reduce<<<6, 256, 0, stream>>>(pmax, pxlog);
  k_combine<<<1, 512, 0, stream>>>(plog, pxlog, glog, out);
}

// Round 4
// 616.068 us; speedup vs baseline: 4.0531x; 2.1355x over previous
//
#include <hip/hip_runtime.h>
#include <hip/hip_bf16.h>
#include <math.h>

#define EPSN 1e-12f

using bf16x8 = __attribute__((ext_vector_type(8))) __bf16;
using f32x4  = __attribute__((ext_vector_type(4))) float;

__device__ __forceinline__ void gload_lds16(const void* g, void* l) {
  __builtin_amdgcn_global_load_lds(
      (const __attribute__((address_space(1))) unsigned int*)g,
      (__attribute__((address_space(3))) unsigned int*)l, 16, 0, 0);
}

// ===== transpose [img][640][100] f32 -> [img*100][640] bf16 =====
// fused: per-image GAP (mean over 100 px) into gap[img*640+c] (if non-null),
//        per-pixel sum-of-squares atomically into sumsq[img*100+p]
__global__ __launch_bounds__(256) void k_transpose_bf16(
    const float* __restrict__ src, __hip_bfloat16* __restrict__ dst,
    float* __restrict__ gap, float* __restrict__ sumsq) {
  __shared__ float tile[64][101];
  int img = blockIdx.x;
  int ct = blockIdx.y;              // channel tile 0..9
  const float* s = src + ((size_t)img * 640 + ct * 64) * 100;
  int t = threadIdx.x;
  #pragma unroll
  for (int i = 0; i < 25; ++i) {
    int j = t + i * 256;
    int c = j / 100, p = j % 100;
    tile[c][p] = s[(size_t)c * 100 + p];
  }
  __syncthreads();
  if (gap != nullptr) {
    int c = t >> 2, part = t & 3;
    float sm = 0.f;
    #pragma unroll
    for (int p = 0; p < 25; ++p) sm += tile[c][part * 25 + p];
    sm += __shfl_xor(sm, 1);
    sm += __shfl_xor(sm, 2);
    if (part == 0) gap[(size_t)img * 640 + ct * 64 + c] = sm * 0.01f;
  }
  if (t < 100) {
    float acc = 0.f;
    #pragma unroll 8
    for (int c = 0; c < 64; ++c) { float v = tile[c][t]; acc = fmaf(v, v, acc); }
    atomicAdd(&sumsq[(size_t)img * 100 + t], acc);
  }
  __hip_bfloat16* d = dst + (size_t)img * 100 * 640 + ct * 64;
  #pragma unroll
  for (int i = 0; i < 25; ++i) {
    int j = t + i * 256;
    int p = j >> 6, c = j & 63;
    d[(size_t)p * 640 + c] = __float2bfloat16(tile[c][p]);
  }
}

// ===== finalize inverse norms from sum-of-squares =====
__global__ void k_finalize_inv(const float* __restrict__ qsq, const float* __restrict__ ssq,
                               float* __restrict__ qinv, float* __restrict__ sinv) {
  int idx = blockIdx.x * 256 + threadIdx.x;
  if (idx < 30000) qinv[idx] = 1.f / (sqrtf(qsq[idx]) + EPSN);
  else if (idx < 40000) { int j = idx - 30000; sinv[j] = 1.f / (sqrtf(ssq[j]) + EPSN); }
}

// ===== proto from support GAP =====
__global__ void k_proto_from_gap(const float* __restrict__ sgap, float* __restrict__ proto) {
  int j = blockIdx.x * 256 + threadIdx.x;
  if (j >= 12800) return;
  int b = j / 3200, r2 = j % 3200, n = r2 / 640, c = r2 % 640;
  float s = 0.f;
  #pragma unroll
  for (int k = 0; k < 5; ++k) s += sgap[(size_t)(b * 25 + n * 5 + k) * 640 + c];
  proto[j] = s * 0.2f;
}

__global__ void k_global_d2(const float* __restrict__ qg, const float* __restrict__ proto,
                            float* __restrict__ glog) {
  int w = blockIdx.x * 4 + (threadIdx.x >> 6);
  int lane = threadIdx.x & 63;
  if (w >= 1500) return;
  int r = w / 5, n = w % 5;
  int b = r / 75;
  const float* qrow = qg + (size_t)r * 640;
  const float* prow = proto + (size_t)(b * 5 + n) * 640;
  float s = 0.f;
  for (int c = lane; c < 640; c += 64) { float dd = qrow[c] - prow[c]; s = fmaf(dd, dd, s); }
  #pragma unroll
  for (int off = 32; off >= 1; off >>= 1) s += __shfl_xor(s, off, 64);
  if (lane == 0) glog[w] = -s;
}

// ===== part path: build SP [b][325][640] =====
__global__ void k_sp_build(const float* __restrict__ spart, float* __restrict__ SP) {
  int idx = blockIdx.x * 256 + threadIdx.x;
  if (idx >= 832000) return;
  int b = idx / (325 * 640);
  int r = idx % (325 * 640);
  int node = r / 640, c = r % 640;
  int s = node / 13, p = node % 13;
  SP[idx] = spart[(size_t)((b * 25 + s) * 640 + c) * 13 + p];
}

// ===== QKV GEMM (fp32) =====
__global__ __launch_bounds__(256) void k_gemm_qkv(
    const float* __restrict__ SP, const float* __restrict__ Wq,
    const float* __restrict__ Wk, const float* __restrict__ Wv,
    float* __restrict__ Qb, float* __restrict__ Kb, float* __restrict__ Vb) {
  __shared__ float A_s[16][65];
  __shared__ float B_s[16][64];
  int mt = blockIdx.x, nt = blockIdx.y;
  int b = blockIdx.z / 3, w = blockIdx.z % 3;
  const float* W = (w == 0) ? Wq : ((w == 1) ? Wk : Wv);
  float* outp = ((w == 0) ? Qb : ((w == 1) ? Kb : Vb)) + (size_t)b * 325 * 640;
  const float* A = SP + (size_t)b * 325 * 640;
  int tid = threadIdx.x;
  int tx = tid & 15, ty = tid >> 4;
  int lch = tid & 15, lr = tid >> 4;
  int bcol = tid & 63, bkr = tid >> 6;
  float acc[4][4] = {};
  for (int c0 = 0; c0 < 640; c0 += 16) {
    __syncthreads();
    #pragma unroll
    for (int i = 0; i < 4; ++i) {
      int r = lr + 16 * i;
      int m = mt * 64 + r;
      A_s[lch][r] = (m < 325) ? A[(size_t)m * 640 + c0 + lch] : 0.f;
    }
    #pragma unroll
    for (int i = 0; i < 4; ++i) {
      int kk = bkr * 4 + i;
      B_s[kk][bcol] = W[(size_t)(c0 + kk) * 640 + nt * 64 + bcol];
    }
    __syncthreads();
    #pragma unroll
    for (int kk = 0; kk < 16; ++kk) {
      float av[4], bv[4];
      #pragma unroll
      for (int i = 0; i < 4; ++i) av[i] = A_s[kk][ty + 16 * i];
      #pragma unroll
      for (int j = 0; j < 4; ++j) bv[j] = B_s[kk][tx + 16 * j];
      #pragma unroll
      for (int i = 0; i < 4; ++i)
        #pragma unroll
        for (int j = 0; j < 4; ++j)
          acc[i][j] = fmaf(av[i], bv[j], acc[i][j]);
    }
  }
  #pragma unroll
  for (int i = 0; i < 4; ++i) {
    int m = mt * 64 + ty + 16 * i;
    if (m < 325) {
      #pragma unroll
      for (int j = 0; j < 4; ++j)
        outp[(size_t)m * 640 + nt * 64 + tx + 16 * j] = acc[i][j];
    }
  }
}

// ===== scores = Q@K^T * 1/sqrt(640) =====
__global__ __launch_bounds__(256) void k_gemm_scores(
    const float* __restrict__ Qb, const float* __restrict__ Kb, float* __restrict__ S) {
  __shared__ float A_s[16][65];
  __shared__ float Bt_s[16][65];
  const float SCALE = 0.03952847075210474f;
  int mt = blockIdx.x, nt = blockIdx.y, b = blockIdx.z;
  const float* A = Qb + (size_t)b * 325 * 640;
  const float* Km = Kb + (size_t)b * 325 * 640;
  int tid = threadIdx.x;
  int tx = tid & 15, ty = tid >> 4;
  int lch = tid & 15, lr = tid >> 4;
  float acc[4][4] = {};
  for (int c0 = 0; c0 < 640; c0 += 16) {
    __syncthreads();
    #pragma unroll
    for (int i = 0; i < 4; ++i) {
      int r = lr + 16 * i;
      int m = mt * 64 + r;
      A_s[lch][r] = (m < 325) ? A[(size_t)m * 640 + c0 + lch] : 0.f;
      int m2 = nt * 64 + r;
      Bt_s[lch][r] = (m2 < 325) ? Km[(size_t)m2 * 640 + c0 + lch] : 0.f;
    }
    __syncthreads();
    #pragma unroll
    for (int kk = 0; kk < 16; ++kk) {
      float av[4], bv[4];
      #pragma unroll
      for (int i = 0; i < 4; ++i) av[i] = A_s[kk][ty + 16 * i];
      #pragma unroll
      for (int j = 0; j < 4; ++j) bv[j] = Bt_s[kk][tx + 16 * j];
      #pragma unroll
      for (int i = 0; i < 4; ++i)
        #pragma unroll
        for (int j = 0; j < 4; ++j)
          acc[i][j] = fmaf(av[i], bv[j], acc[i][j]);
    }
  }
  #pragma unroll
  for (int i = 0; i < 4; ++i) {
    int m = mt * 64 + ty + 16 * i;
    if (m >= 325) continue;
    #pragma unroll
    for (int j = 0; j < 4; ++j) {
      int col = nt * 64 + tx + 16 * j;
      if (col < 325) S[(size_t)b * 105625 + (size_t)m * 325 + col] = acc[i][j] * SCALE;
    }
  }
}

// ===== row softmax over 325 =====
__global__ void k_softmax_rows(float* __restrict__ S) {
  int w = blockIdx.x * 4 + (threadIdx.x >> 6);
  int lane = threadIdx.x & 63;
  if (w >= 1300) return;
  float* row = S + (size_t)w * 325;
  float ev[6];
  float mx = -1e30f;
  #pragma unroll
  for (int j = 0; j < 6; ++j) {
    int c = lane + 64 * j;
    float x = (c < 325) ? row[c] : -1e30f;
    ev[j] = x;
    mx = fmaxf(mx, x);
  }
  #pragma unroll
  for (int off = 32; off >= 1; off >>= 1) mx = fmaxf(mx, __shfl_xor(mx, off, 64));
  float sum = 0.f;
  #pragma unroll
  for (int j = 0; j < 6; ++j) {
    int c = lane + 64 * j;
    if (c < 325) { float e = expf(ev[j] - mx); ev[j] = e; sum += e; }
    else ev[j] = 0.f;
  }
  #pragma unroll
  for (int off = 32; off >= 1; off >>= 1) sum += __shfl_xor(sum, off, 64);
  float rinv = 1.f / sum;
  #pragma unroll
  for (int j = 0; j < 6; ++j) {
    int c = lane + 64 * j;
    if (c < 325) row[c] = ev[j] * rinv;
  }
}

// ===== spo = att@V + SP =====
__global__ __launch_bounds__(256) void k_gemm_av(
    const float* __restrict__ S, const float* __restrict__ Vb,
    const float* __restrict__ SP, float* __restrict__ spo) {
  __shared__ float A_s[16][65];
  __shared__ float B_s[16][64];
  int mt = blockIdx.x, nt = blockIdx.y, b = blockIdx.z;
  const float* A = S + (size_t)b * 105625;
  const float* Bv = Vb + (size_t)b * 325 * 640;
  int tid = threadIdx.x;
  int tx = tid & 15, ty = tid >> 4;
  int lch = tid & 15, lr = tid >> 4;
  int bcol = tid & 63, bkr = tid >> 6;
  float acc[4][4] = {};
  for (int c0 = 0; c0 < 325; c0 += 16) {
    __syncthreads();
    #pragma unroll
    for (int i = 0; i < 4; ++i) {
      int r = lr + 16 * i;
      int m = mt * 64 + r;
      int kidx = c0 + lch;
      A_s[lch][r] = (m < 325 && kidx < 325) ? A[(size_t)m * 325 + kidx] : 0.f;
    }
    #pragma unroll
    for (int i = 0; i < 4; ++i) {
      int kk = bkr * 4 + i;
      int kidx = c0 + kk;
      B_s[kk][bcol] = (kidx < 325) ? Bv[(size_t)kidx * 640 + nt * 64 + bcol] : 0.f;
    }
    __syncthreads();
    #pragma unroll
    for (int kk = 0; kk < 16; ++kk) {
      float av[4], bv[4];
      #pragma unroll
      for (int i = 0; i < 4; ++i) av[i] = A_s[kk][ty + 16 * i];
      #pragma unroll
      for (int j = 0; j < 4; ++j) bv[j] = B_s[kk][tx + 16 * j];
      #pragma unroll
      for (int i = 0; i < 4; ++i)
        #pragma unroll
        for (int j = 0; j < 4; ++j)
          acc[i][j] = fmaf(av[i], bv[j], acc[i][j]);
    }
  }
  #pragma unroll
  for (int i = 0; i < 4; ++i) {
    int m = mt * 64 + ty + 16 * i;
    if (m >= 325) continue;
    #pragma unroll
    for (int j = 0; j < 4; ++j) {
      size_t idx = (size_t)b * 325 * 640 + (size_t)m * 640 + nt * 64 + tx + 16 * j;
      spo[idx] = acc[i][j] + SP[idx];
    }
  }
}

// ===== pack spo -> normalized bf16 Spb[b][325][640] (norm fused) =====
__global__ __launch_bounds__(256) void k_pack_sp(
    const float* __restrict__ spo, __hip_bfloat16* __restrict__ Spb) {
  __shared__ float red[4];
  __shared__ float s_inv;
  int node = blockIdx.x;            // 0..1299
  const float* row = spo + (size_t)node * 640;
  int t = threadIdx.x;
  float s = 0.f;
  for (int e = t; e < 640; e += 256) { float v = row[e]; s = fmaf(v, v, s); }
  #pragma unroll
  for (int off = 32; off >= 1; off >>= 1) s += __shfl_xor(s, off, 64);
  if ((t & 63) == 0) red[t >> 6] = s;
  __syncthreads();
  if (t == 0) s_inv = 1.f / (sqrtf(red[0] + red[1] + red[2] + red[3]) + EPSN);
  __syncthreads();
  float inv = s_inv;
  for (int e = t; e < 640; e += 256)
    Spb[(size_t)node * 640 + e] = __float2bfloat16(row[e] * inv);
}

// ===== pack qpart -> normalized bf16 Qpb[b][975][640] (transpose+norm fused) ==
__global__ __launch_bounds__(256) void k_pack_qp(
    const float* __restrict__ qpart, __hip_bfloat16* __restrict__ Qpb) {
  __shared__ float lds0[8320];
  __shared__ float pinv[13];
  int bq = blockIdx.x;              // 0..299
  const float* src = qpart + (size_t)bq * 8320;
  int t = threadIdx.x;
  #pragma unroll
  for (int i = 0; i < 33; ++i) {
    int e = t + i * 256;
    if (e < 8320) lds0[e] = src[e];
  }
  __syncthreads();
  int g = t >> 4, l = t & 15;
  if (g < 13) {
    float s = 0.f;
    for (int c = l; c < 640; c += 16) { float v = lds0[c * 13 + g]; s = fmaf(v, v, s); }
    #pragma unroll
    for (int off = 8; off >= 1; off >>= 1) s += __shfl_xor(s, off, 16);
    if (l == 0) pinv[g] = 1.f / (sqrtf(s) + EPSN);
  }
  __syncthreads();
  #pragma unroll
  for (int i = 0; i < 33; ++i) {
    int j = t + i * 256;
    if (j < 8320) {
      int p = j / 640, c = j % 640;
      Qpb[((size_t)bq * 13 + p) * 640 + c] = __float2bfloat16(lds0[c * 13 + p] * pinv[p]);
    }
  }
}

// ===== part GEMM: Cpart[b][1024][384] = Qpb x Spb^T (bf16 MFMA) =====
// grid: (ntile 0..2, mtile 0..7, b), block 256 (4 waves)
__global__ __launch_bounds__(256) void k_part_mfma(
    const __hip_bfloat16* __restrict__ Qpb, const __hip_bfloat16* __restrict__ Spb,
    float* __restrict__ Cpart) {
  __shared__ __align__(16) __bf16 ldsA[128 * 64];
  __shared__ __align__(16) __bf16 ldsB[128 * 64];
  int nt = blockIdx.x, mt = blockIdx.y, b = blockIdx.z;
  int tid = threadIdx.x;
  int w = tid >> 6, lane = tid & 63;
  int l15 = lane & 15, l4 = lane >> 4;
  const __hip_bfloat16* A = Qpb + (size_t)b * 975 * 640;
  const __hip_bfloat16* B = Spb + (size_t)b * 325 * 640;

  f32x4 acc[2][8];
  #pragma unroll
  for (int i = 0; i < 2; ++i)
    #pragma unroll
    for (int j = 0; j < 8; ++j) acc[i][j] = (f32x4){0.f, 0.f, 0.f, 0.f};

  for (int kt = 0; kt < 10; ++kt) {
    int c0 = kt * 64;
    __syncthreads();
    #pragma unroll
    for (int j = 0; j < 4; ++j) {
      int ci = w * 256 + j * 64 + lane;
      int row = ci >> 3, kc = ci & 7;
      int srcc = kc ^ (row & 7);
      int ar = mt * 128 + row; if (ar > 974) ar = 974;
      gload_lds16(A + (size_t)ar * 640 + c0 + srcc * 8,
                  (char*)ldsA + (w * 256 + j * 64) * 16);
    }
    #pragma unroll
    for (int j = 0; j < 4; ++j) {
      int ci = w * 256 + j * 64 + lane;
      int row = ci >> 3, kc = ci & 7;
      int srcc = kc ^ (row & 7);
      int br = nt * 128 + row; if (br > 324) br = 324;
      gload_lds16(B + (size_t)br * 640 + c0 + srcc * 8,
                  (char*)ldsB + (w * 256 + j * 64) * 16);
    }
    __syncthreads();
    #pragma unroll
    for (int ks = 0; ks < 2; ++ks) {
      int chunk = ks * 4 + l4;
      bf16x8 af[2];
      #pragma unroll
      for (int mf = 0; mf < 2; ++mf) {
        int row = w * 32 + mf * 16 + l15;
        af[mf] = *(const bf16x8*)((const char*)ldsA + row * 128 + ((chunk ^ (row & 7)) << 4));
      }
      #pragma unroll
      for (int nf = 0; nf < 8; ++nf) {
        int col = nf * 16 + l15;
        bf16x8 bv = *(const bf16x8*)((const char*)ldsB + col * 128 + ((chunk ^ (col & 7)) << 4));
        #pragma unroll
        for (int mf = 0; mf < 2; ++mf)
          acc[mf][nf] = __builtin_amdgcn_mfma_f32_16x16x32_bf16(af[mf], bv, acc[mf][nf], 0, 0, 0);
      }
    }
  }
  #pragma unroll
  for (int mf = 0; mf < 2; ++mf)
    #pragma unroll
    for (int r = 0; r < 4; ++r) {
      int row = mt * 128 + w * 32 + mf * 16 + l4 * 4 + r;
      #pragma unroll
      for (int nf = 0; nf < 8; ++nf) {
        int col = nt * 128 + nf * 16 + l15;
        Cpart[((size_t)b * 1024 + row) * 384 + col] = acc[mf][nf][r];
      }
    }
}

// ===== part reduce: plog[bq*5+n] = sum_qp max_scol Cpart =====
__global__ void k_part_reduce(const float* __restrict__ Cpart, float* __restrict__ plog) {
  int w = blockIdx.x * 4 + (threadIdx.x >> 6);
  int lane = threadIdx.x & 63;
  if (w >= 1500) return;
  int bq = w / 5, n = w % 5;
  int b = bq / 75, q = bq % 75;
  int qp = lane >> 2, c4 = lane & 3;
  float m = -1e30f;
  if (qp < 13) {
    const float* row = Cpart + ((size_t)b * 1024 + q * 13 + qp) * 384 + n * 65;
    int hi = c4 * 17 + 17; if (hi > 65) hi = 65;
    for (int cc = c4 * 17; cc < hi; ++cc) m = fmaxf(m, row[cc]);
  }
  m = fmaxf(m, __shfl_xor(m, 1));
  m = fmaxf(m, __shfl_xor(m, 2));
  float contrib = (qp < 13 && c4 == 0) ? m : 0.f;
  #pragma unroll
  for (int off = 32; off >= 1; off >>= 1) contrib += __shfl_xor(contrib, off, 64);
  if (lane == 0) plog[w] = contrib;
}

// ===== pixel GEMM via bf16 MFMA, fused strip-max =====
__global__ __launch_bounds__(256) void k_pixel_mfma(
    const __hip_bfloat16* __restrict__ Qn, const __hip_bfloat16* __restrict__ Sn,
    const float* __restrict__ qinv, const float* __restrict__ sinv,
    float* __restrict__ pmax) {
  __shared__ __align__(16) __bf16 ldsA[128 * 64];
  __shared__ __align__(16) __bf16 ldsB[128 * 64];
  int x = blockIdx.x;
  int strip = x / 5, n = x % 5;
  int qt = blockIdx.y;
  int b = blockIdx.z;
  int tid = threadIdx.x;
  int w = tid >> 6, lane = tid & 63;
  int l15 = lane & 15, l4 = lane >> 4;

  const __hip_bfloat16* QnB = Qn + (size_t)b * 7500 * 640;
  const __hip_bfloat16* SnB = Sn + ((size_t)b * 2500 + n * 500) * 640;

  f32x4 acc[2][8];
  #pragma unroll
  for (int i = 0; i < 2; ++i)
    #pragma unroll
    for (int j = 0; j < 8; ++j) acc[i][j] = (f32x4){0.f, 0.f, 0.f, 0.f};

  for (int kt = 0; kt < 10; ++kt) {
    int c0 = kt * 64;
    __syncthreads();
    #pragma unroll
    for (int j = 0; j < 4; ++j) {
      int ci = w * 256 + j * 64 + lane;
      int row = ci >> 3, kc = ci & 7;
      int srcc = kc ^ (row & 7);
      int qrow = qt * 128 + row; if (qrow > 7499) qrow = 7499;
      gload_lds16(QnB + (size_t)qrow * 640 + c0 + srcc * 8,
                  (char*)ldsA + (w * 256 + j * 64) * 16);
    }
    #pragma unroll
    for (int j = 0; j < 4; ++j) {
      int ci = w * 256 + j * 64 + lane;
      int row = ci >> 3, kc = ci & 7;
      int srcc = kc ^ (row & 7);
      int srow = strip * 128 + row; if (srow > 499) srow = 499;
      gload_lds16(SnB + (size_t)srow * 640 + c0 + srcc * 8,
                  (char*)ldsB + (w * 256 + j * 64) * 16);
    }
    __syncthreads();
    #pragma unroll
    for (int ks = 0; ks < 2; ++ks) {
      int chunk = ks * 4 + l4;
      bf16x8 af[2];
      #pragma unroll
      for (int mf = 0; mf < 2; ++mf) {
        int row = w * 32 + mf * 16 + l15;
        af[mf] = *(const bf16x8*)((const char*)ldsA + row * 128 + ((chunk ^ (row & 7)) << 4));
      }
      #pragma unroll
      for (int nf = 0; nf < 8; ++nf) {
        int col = nf * 16 + l15;
        bf16x8 bv = *(const bf16x8*)((const char*)ldsB + col * 128 + ((chunk ^ (col & 7)) << 4));
        #pragma unroll
        for (int mf = 0; mf < 2; ++mf)
          acc[mf][nf] = __builtin_amdgcn_mfma_f32_16x16x32_bf16(af[mf], bv, acc[mf][nf], 0, 0, 0);
      }
    }
  }

  int z = b * 5 + n;
  float sscale[8]; bool svalid[8];
  #pragma unroll
  for (int nf = 0; nf < 8; ++nf) {
    int scol = strip * 128 + nf * 16 + l15;
    svalid[nf] = scol < 500;
    sscale[nf] = sinv[b * 2500 + n * 500 + (svalid[nf] ? scol : 0)];
  }
  #pragma unroll
  for (int mf = 0; mf < 2; ++mf) {
    #pragma unroll
    for (int r = 0; r < 4; ++r) {
      int row = qt * 128 + w * 32 + mf * 16 + l4 * 4 + r;
      bool rvalid = row < 7500;
      float qs = qinv[b * 7500 + (rvalid ? row : 0)];
      float m = -1e30f;
      #pragma unroll
      for (int nf = 0; nf < 8; ++nf) {
        float v = acc[mf][nf][r] * qs * sscale[nf];
        if (svalid[nf]) m = fmaxf(m, v);
      }
      #pragma unroll
      for (int off = 8; off >= 1; off >>= 1) m = fmaxf(m, __shfl_xor(m, off));
      if (l15 == 0 && rvalid)
        pmax[((size_t)z * 7500 + row) * 4 + strip] = m;
    }
  }
}

// ===== pixel reduce =====
__global__ void k_pixel_reduce(const float* __restrict__ pmax, float* __restrict__ pxlog) {
  int t = blockIdx.x * 256 + threadIdx.x;
  if (t >= 1500) return;
  int r = t / 5, n = t % 5;
  int b = r / 75, q = r % 75;
  const float* base = pmax + (size_t)((b * 5 + n) * 7500 + q * 100) * 4;
  float s = 0.f;
  for (int p = 0; p < 100; ++p) {
    float m = fmaxf(fmaxf(base[p * 4], base[p * 4 + 1]), fmaxf(base[p * 4 + 2], base[p * 4 + 3]));
    s += m;
  }
  pxlog[t] = s;
}

// ===== final combine =====
__device__ inline void softmax5_add(const float* l, float wgt, float* acc) {
  float m = fmaxf(fmaxf(fmaxf(l[0], l[1]), fmaxf(l[2], l[3])), l[4]);
  float e[5]; float s = 0.f;
  #pragma unroll
  for (int i = 0; i < 5; ++i) { e[i] = expf(l[i] - m); s += e[i]; }
  float r = wgt / s;
  #pragma unroll
  for (int i = 0; i < 5; ++i) acc[i] += e[i] * r;
}

__global__ void k_combine(const float* __restrict__ plog, const float* __restrict__ pxlog,
                          const float* __restrict__ glog, float* __restrict__ out) {
  int t = blockIdx.x * blockDim.x + threadIdx.x;
  if (t >= 300) return;
  float accv[5] = {0.f, 0.f, 0.f, 0.f, 0.f};
  float l[5];
  #pragma unroll
  for (int i = 0; i < 5; ++i) l[i] = plog[t * 5 + i];
  softmax5_add(l, 1.0f, accv);
  #pragma unroll
  for (int i = 0; i < 5; ++i) l[i] = pxlog[t * 5 + i];
  softmax5_add(l, 0.5f, accv);
  #pragma unroll
  for (int i = 0; i < 5; ++i) l[i] = glog[t * 5 + i];
  softmax5_add(l, 0.5f, accv);
  #pragma unroll
  for (int i = 0; i < 5; ++i) out[t * 5 + i] = accv[i];
}

// ===== launch =====
extern "C" void kernel_launch(void* const* d_in, const int* in_sizes, int n_in,
                              void* d_out, int out_size, void* d_ws, size_t ws_size,
                              hipStream_t stream) {
  (void)in_sizes; (void)n_in; (void)out_size; (void)ws_size;
  const float* support = (const float*)d_in[0];  // [4,25,640,10,10]
  const float* query   = (const float*)d_in[1];  // [4,75,640,10,10]
  const float* spart   = (const float*)d_in[2];  // [4,25,640,13,1]
  const float* qpart   = (const float*)d_in[3];  // [4,75,640,13,1]
  const float* Wq      = (const float*)d_in[4];
  const float* Wk      = (const float*)d_in[5];
  const float* Wv      = (const float*)d_in[6];
  float* out = (float*)d_out;                    // [300,5]
  float* ws = (float*)d_ws;

  size_t o = 0;
  __hip_bfloat16* Qn  = (__hip_bfloat16*)(ws + o); o += 9600000;  // 4*7500*640 bf16
  __hip_bfloat16* Sn  = (__hip_bfloat16*)(ws + o); o += 3200000;  // 4*2500*640 bf16
  __hip_bfloat16* Qpb = (__hip_bfloat16*)(ws + o); o += 1248000;  // 4*975*640 bf16
  __hip_bfloat16* Spb = (__hip_bfloat16*)(ws + o); o += 416000;   // 4*325*640 bf16
  float* qsq   = ws + o; o += 30000;
  float* ssq   = ws + o; o += 10000;
  float* qinv  = ws + o; o += 30000;
  float* sinv  = ws + o; o += 10000;
  float* qg    = ws + o; o += 192000;
  float* sgap  = ws + o; o += 64000;
  float* proto = ws + o; o += 12800;
  float* SP    = ws + o; o += 832000;
  float* Qb    = ws + o; o += 832000;   // dead after k_gemm_scores
  float* Kb    = ws + o; o += 832000;   // dead after k_gemm_scores
  float* Vb    = ws + o; o += 832000;
  float* S     = ws + o; o += 422500;
  float* spo   = ws + o; o += 832000;
  float* pmax  = ws + o; o += 600000;
  float* plog  = ws + o; o += 1500;
  float* pxlog = ws + o; o += 1500;
  float* glog  = ws + o; o += 1500;
  float* Cpart = Qb;                    // alias: 4*1024*384 = 1.573M < Qb+Kb (1.664M)

  hipMemsetAsync(qsq, 0, 40000 * sizeof(float), stream);  // qsq+ssq contiguous
  k_transpose_bf16<<<dim3(300, 10), 256, 0, stream>>>(query, Qn, qg, qsq);
  k_transpose_bf16<<<dim3(100, 10), 256, 0, stream>>>(support, Sn, sgap, ssq);
  k_finalize_inv<<<157, 256, 0, stream>>>(qsq, ssq, qinv, sinv);
  k_proto_from_gap<<<50, 256, 0, stream>>>(sgap, proto);
  k_sp_build<<<3250, 256, 0, stream>>>(spart, SP);
  k_gemm_qkv<<<dim3(6, 10, 12), 256, 0, stream>>>(SP, Wq, Wk, Wv, Qb, Kb, Vb);
  k_gemm_scores<<<dim3(6, 6, 4), 256, 0, stream>>>(Qb, Kb, S);
  k_softmax_rows<<<325, 256, 0, stream>>>(S);
  k_gemm_av<<<dim3(6, 10, 4), 256, 0, stream>>>(S, Vb, SP, spo);
  k_pack_sp<<<1300, 256, 0, stream>>>(spo, Spb);
  k_pack_qp<<<300, 256, 0, stream>>>(qpart, Qpb);
  k_part_mfma<<<dim3(3, 8, 4), 256, 0, stream>>>(Qpb, Spb, Cpart);
  k_part_reduce<<<375, 256, 0, stream>>>(Cpart, plog);
  k_global_d2<<<375, 256, 0, stream>>>(qg, proto, glog);
  k_pixel_mfma<<<dim3(20, 59, 4), 256, 0, stream>>>(Qn, Sn, qinv, sinv, pmax);
  k_pixel_reduce<<<6, 256, 0, stream>>>(pmax, pxlog);
  k_combine<<<1, 512, 0, stream>>>(plog, pxlog, glog, out);
}

// Round 9
// 480.585 us; speedup vs baseline: 5.1958x; 1.2819x over previous
//
#include <hip/hip_runtime.h>
#include <hip/hip_bf16.h>
#include <math.h>

#define EPSN 1e-12f

using bf16x8 = __attribute__((ext_vector_type(8))) __bf16;
using f32x4  = __attribute__((ext_vector_type(4))) float;

__device__ __forceinline__ void gload_lds16(const void* g, void* l) {
  __builtin_amdgcn_global_load_lds(
      (const __attribute__((address_space(1))) unsigned int*)g,
      (__attribute__((address_space(3))) unsigned int*)l, 16, 0, 0);
}

// stage a 128x64 bf16 tile (rows row0.., clamped to maxrow) into swizzled LDS
__device__ __forceinline__ void stage128(const __hip_bfloat16* __restrict__ src,
                                         size_t ldk, int row0, int maxrow, int c0,
                                         __bf16* lds, int w, int lane) {
  #pragma unroll
  for (int j = 0; j < 4; ++j) {
    int ci = w * 256 + j * 64 + lane;
    int row = ci >> 3, kc = ci & 7;
    int srcc = kc ^ (row & 7);
    int r = row0 + row; if (r > maxrow) r = maxrow;
    gload_lds16(src + (size_t)r * ldk + c0 + srcc * 8, (char*)lds + (size_t)ci * 16);
  }
}

// 64x64 wave tile: 4x4 fragments, one K=64 chunk from swizzled LDS
__device__ __forceinline__ void compute64(const __bf16* ldsA, const __bf16* ldsB,
                                          int wr, int wc, int l15, int l4,
                                          f32x4 acc[4][4]) {
  #pragma unroll
  for (int ks = 0; ks < 2; ++ks) {
    int chunk = ks * 4 + l4;
    bf16x8 af[4], bv[4];
    #pragma unroll
    for (int mf = 0; mf < 4; ++mf) {
      int row = wr * 64 + mf * 16 + l15;
      af[mf] = *(const bf16x8*)((const char*)ldsA + row * 128 + ((chunk ^ (row & 7)) << 4));
    }
    #pragma unroll
    for (int nf = 0; nf < 4; ++nf) {
      int col = wc * 64 + nf * 16 + l15;
      bv[nf] = *(const bf16x8*)((const char*)ldsB + col * 128 + ((chunk ^ (col & 7)) << 4));
    }
    #pragma unroll
    for (int mf = 0; mf < 4; ++mf)
      #pragma unroll
      for (int nf = 0; nf < 4; ++nf)
        acc[mf][nf] = __builtin_amdgcn_mfma_f32_16x16x32_bf16(af[mf], bv[nf], acc[mf][nf], 0, 0, 0);
  }
}

// ===== transpose [img][640][100] f32 -> [img*100][640] bf16, fused GAP + sumsq
__global__ __launch_bounds__(256) void k_transpose_bf16(
    const float* __restrict__ src, __hip_bfloat16* __restrict__ dst,
    float* __restrict__ gap, float* __restrict__ sumsq) {
  __shared__ float tile[64][101];
  int img = blockIdx.x;
  int ct = blockIdx.y;
  const float* s = src + ((size_t)img * 640 + ct * 64) * 100;
  int t = threadIdx.x;
  #pragma unroll
  for (int i = 0; i < 25; ++i) {
    int j = t + i * 256;
    int c = j / 100, p = j % 100;
    tile[c][p] = s[(size_t)c * 100 + p];
  }
  __syncthreads();
  if (gap != nullptr) {
    int c = t >> 2, part = t & 3;
    float sm = 0.f;
    #pragma unroll
    for (int p = 0; p < 25; ++p) sm += tile[c][part * 25 + p];
    sm += __shfl_xor(sm, 1);
    sm += __shfl_xor(sm, 2);
    if (part == 0) gap[(size_t)img * 640 + ct * 64 + c] = sm * 0.01f;
  }
  if (t < 100) {
    float acc = 0.f;
    #pragma unroll 8
    for (int c = 0; c < 64; ++c) { float v = tile[c][t]; acc = fmaf(v, v, acc); }
    atomicAdd(&sumsq[(size_t)img * 100 + t], acc);
  }
  __hip_bfloat16* d = dst + (size_t)img * 100 * 640 + ct * 64;
  #pragma unroll
  for (int i = 0; i < 25; ++i) {
    int j = t + i * 256;
    int p = j >> 6, c = j & 63;
    d[(size_t)p * 640 + c] = __float2bfloat16(tile[c][p]);
  }
}

// ===== in-place: x = 1/(sqrt(x)+eps) over qsq(30000)+ssq(10000) =====
__global__ void k_finalize_inv(float* __restrict__ sq) {
  int idx = blockIdx.x * 256 + threadIdx.x;
  if (idx < 40000) sq[idx] = 1.f / (sqrtf(sq[idx]) + EPSN);
}

// ===== fused proto + global d2 =====
__global__ __launch_bounds__(256) void k_proto_d2(
    const float* __restrict__ sgap, const float* __restrict__ qg,
    float* __restrict__ glog) {
  __shared__ float proto[640];
  int bn = blockIdx.x; int b = bn / 5, n = bn % 5;
  int t = threadIdx.x;
  for (int c = t; c < 640; c += 256) {
    float s = 0.f;
    #pragma unroll
    for (int k = 0; k < 5; ++k) s += sgap[(size_t)(b * 25 + n * 5 + k) * 640 + c];
    proto[c] = s * 0.2f;
  }
  __syncthreads();
  int w = t >> 6, lane = t & 63;
  for (int q = w; q < 75; q += 4) {
    const float* qrow = qg + (size_t)(b * 75 + q) * 640;
    float s = 0.f;
    for (int c = lane; c < 640; c += 64) { float d = qrow[c] - proto[c]; s = fmaf(d, d, s); }
    #pragma unroll
    for (int off = 32; off >= 1; off >>= 1) s += __shfl_xor(s, off, 64);
    if (lane == 0) glog[(b * 75 + q) * 5 + n] = -s;
  }
}

// ===== build SP f32 + SPa bf16 [b][325][640] =====
__global__ void k_sp_build(const float* __restrict__ spart, float* __restrict__ SP,
                           __hip_bfloat16* __restrict__ SPa) {
  int idx = blockIdx.x * 256 + threadIdx.x;
  if (idx >= 832000) return;
  int b = idx / (325 * 640);
  int r = idx % (325 * 640);
  int node = r / 640, c = r % 640;
  int s = node / 13, p = node % 13;
  float v = spart[(size_t)((b * 25 + s) * 640 + c) * 13 + p];
  SP[idx] = v;
  SPa[idx] = __float2bfloat16(v);
}

// ===== pack W [cin][cout] f32 -> Wt [w][cout][cin] bf16 =====
__global__ __launch_bounds__(256) void k_w_pack(
    const float* __restrict__ Wq, const float* __restrict__ Wk,
    const float* __restrict__ Wv, __hip_bfloat16* __restrict__ Wt) {
  __shared__ float tile[64][65];
  int t = blockIdx.x;           // 0..99
  int w = blockIdx.y;
  const float* W = (w == 0) ? Wq : ((w == 1) ? Wk : Wv);
  int rt = t / 10, ct = t % 10; // rt: cin tile, ct: cout tile
  int tid = threadIdx.x;
  int cc = tid & 63;
  #pragma unroll
  for (int i = 0; i < 16; ++i) {
    int rr = i * 4 + (tid >> 6);
    tile[rr][cc] = W[(size_t)(rt * 64 + rr) * 640 + ct * 64 + cc];
  }
  __syncthreads();
  #pragma unroll
  for (int i = 0; i < 16; ++i) {
    int rr = i * 4 + (tid >> 6);
    Wt[((size_t)w * 640 + ct * 64 + rr) * 640 + rt * 64 + cc] = __float2bfloat16(tile[cc][rr]);
  }
}

// ===== QKV MFMA: [325x640] @ Wt^T -> Qb16/Kb16 bf16 [node][cout], Vt16 [cout][384]
__global__ __launch_bounds__(256) void k_qkv_mfma(
    const __hip_bfloat16* __restrict__ SPa, const __hip_bfloat16* __restrict__ Wt,
    __hip_bfloat16* __restrict__ Qb16, __hip_bfloat16* __restrict__ Kb16,
    __hip_bfloat16* __restrict__ Vt16) {
  __shared__ __align__(16) __bf16 ldsA[128 * 64];
  __shared__ __align__(16) __bf16 ldsB[128 * 64];
  int nt = blockIdx.x, mt = blockIdx.y, z = blockIdx.z;
  int b = z / 3, w3 = z % 3;
  int tid = threadIdx.x;
  int w = tid >> 6, lane = tid & 63;
  int l15 = lane & 15, l4 = lane >> 4;
  int wr = w >> 1, wc = w & 1;
  const __hip_bfloat16* A = SPa + (size_t)b * 325 * 640;
  const __hip_bfloat16* B = Wt + (size_t)w3 * 640 * 640;

  f32x4 acc[4][4];
  #pragma unroll
  for (int i = 0; i < 4; ++i)
    #pragma unroll
    for (int j = 0; j < 4; ++j) acc[i][j] = (f32x4){0.f, 0.f, 0.f, 0.f};

  for (int kt = 0; kt < 10; ++kt) {
    int c0 = kt * 64;
    __syncthreads();
    stage128(A, 640, mt * 128, 324, c0, ldsA, w, lane);
    stage128(B, 640, nt * 128, 639, c0, ldsB, w, lane);
    __syncthreads();
    compute64(ldsA, ldsB, wr, wc, l15, l4, acc);
  }
  __hip_bfloat16* Qo = Qb16 + (size_t)b * 208000;
  __hip_bfloat16* Ko = Kb16 + (size_t)b * 208000;
  __hip_bfloat16* Vo = Vt16 + (size_t)b * 245760;
  #pragma unroll
  for (int mf = 0; mf < 4; ++mf)
    #pragma unroll
    for (int r = 0; r < 4; ++r) {
      int row = mt * 128 + wr * 64 + mf * 16 + l4 * 4 + r;
      if (row >= 325) continue;
      #pragma unroll
      for (int nf = 0; nf < 4; ++nf) {
        int col = nt * 128 + wc * 64 + nf * 16 + l15;
        float v = acc[mf][nf][r];
        if (w3 == 0)      Qo[(size_t)row * 640 + col] = __float2bfloat16(v);
        else if (w3 == 1) Ko[(size_t)row * 640 + col] = __float2bfloat16(v);
        else              Vo[(size_t)col * 384 + row] = __float2bfloat16(v);
      }
    }
}

// ===== scores MFMA: S[b][325][325] f32 = (Q@K^T)/sqrt(640) =====
__global__ __launch_bounds__(256) void k_scores_mfma(
    const __hip_bfloat16* __restrict__ Qb16, const __hip_bfloat16* __restrict__ Kb16,
    float* __restrict__ S) {
  __shared__ __align__(16) __bf16 ldsA[128 * 64];
  __shared__ __align__(16) __bf16 ldsB[128 * 64];
  const float SCALE = 0.03952847075210474f;
  int nt = blockIdx.x, mt = blockIdx.y, b = blockIdx.z;
  int tid = threadIdx.x;
  int w = tid >> 6, lane = tid & 63;
  int l15 = lane & 15, l4 = lane >> 4;
  int wr = w >> 1, wc = w & 1;
  const __hip_bfloat16* A = Qb16 + (size_t)b * 208000;
  const __hip_bfloat16* B = Kb16 + (size_t)b * 208000;
  f32x4 acc[4][4];
  #pragma unroll
  for (int i = 0; i < 4; ++i)
    #pragma unroll
    for (int j = 0; j < 4; ++j) acc[i][j] = (f32x4){0.f, 0.f, 0.f, 0.f};
  for (int kt = 0; kt < 10; ++kt) {
    int c0 = kt * 64;
    __syncthreads();
    stage128(A, 640, mt * 128, 324, c0, ldsA, w, lane);
    stage128(B, 640, nt * 128, 324, c0, ldsB, w, lane);
    __syncthreads();
    compute64(ldsA, ldsB, wr, wc, l15, l4, acc);
  }
  float* So = S + (size_t)b * 105625;
  #pragma unroll
  for (int mf = 0; mf < 4; ++mf)
    #pragma unroll
    for (int r = 0; r < 4; ++r) {
      int row = mt * 128 + wr * 64 + mf * 16 + l4 * 4 + r;
      if (row >= 325) continue;
      #pragma unroll
      for (int nf = 0; nf < 4; ++nf) {
        int col = nt * 128 + wc * 64 + nf * 16 + l15;
        if (col < 325) So[(size_t)row * 325 + col] = acc[mf][nf][r] * SCALE;
      }
    }
}

// ===== row softmax over 325 -> attb bf16 [row][384], zero-padded =====
__global__ void k_softmax_attb(const float* __restrict__ S, __hip_bfloat16* __restrict__ attb) {
  int w = blockIdx.x * 4 + (threadIdx.x >> 6);
  int lane = threadIdx.x & 63;
  if (w >= 1300) return;
  const float* row = S + (size_t)w * 325;
  float ev[6];
  float mx = -1e30f;
  #pragma unroll
  for (int j = 0; j < 6; ++j) {
    int c = lane + 64 * j;
    float x = (c < 325) ? row[c] : -1e30f;
    ev[j] = x;
    mx = fmaxf(mx, x);
  }
  #pragma unroll
  for (int off = 32; off >= 1; off >>= 1) mx = fmaxf(mx, __shfl_xor(mx, off, 64));
  float sum = 0.f;
  #pragma unroll
  for (int j = 0; j < 6; ++j) {
    int c = lane + 64 * j;
    if (c < 325) { float e = expf(ev[j] - mx); ev[j] = e; sum += e; }
    else ev[j] = 0.f;
  }
  #pragma unroll
  for (int off = 32; off >= 1; off >>= 1) sum += __shfl_xor(sum, off, 64);
  float rinv = 1.f / sum;
  __hip_bfloat16* o = attb + (size_t)w * 384;
  #pragma unroll
  for (int j = 0; j < 6; ++j) {
    int c = lane + 64 * j;
    o[c] = __float2bfloat16((c < 325) ? ev[j] * rinv : 0.f);
  }
}

// ===== AV MFMA: spo f32 [node][640] = attb @ Vt^T + SP =====
__global__ __launch_bounds__(256) void k_av_mfma(
    const __hip_bfloat16* __restrict__ attb, const __hip_bfloat16* __restrict__ Vt16,
    const float* __restrict__ SP, float* __restrict__ spo) {
  __shared__ __align__(16) __bf16 ldsA[128 * 64];
  __shared__ __align__(16) __bf16 ldsB[128 * 64];
  int nt = blockIdx.x, mt = blockIdx.y, b = blockIdx.z;
  int tid = threadIdx.x;
  int w = tid >> 6, lane = tid & 63;
  int l15 = lane & 15, l4 = lane >> 4;
  int wr = w >> 1, wc = w & 1;
  const __hip_bfloat16* A = attb + (size_t)b * 325 * 384;
  const __hip_bfloat16* B = Vt16 + (size_t)b * 245760;
  f32x4 acc[4][4];
  #pragma unroll
  for (int i = 0; i < 4; ++i)
    #pragma unroll
    for (int j = 0; j < 4; ++j) acc[i][j] = (f32x4){0.f, 0.f, 0.f, 0.f};
  for (int kt = 0; kt < 6; ++kt) {
    int c0 = kt * 64;
    __syncthreads();
    stage128(A, 384, mt * 128, 324, c0, ldsA, w, lane);
    stage128(B, 384, nt * 128, 639, c0, ldsB, w, lane);
    __syncthreads();
    compute64(ldsA, ldsB, wr, wc, l15, l4, acc);
  }
  #pragma unroll
  for (int mf = 0; mf < 4; ++mf)
    #pragma unroll
    for (int r = 0; r < 4; ++r) {
      int row = mt * 128 + wr * 64 + mf * 16 + l4 * 4 + r;
      if (row >= 325) continue;
      #pragma unroll
      for (int nf = 0; nf < 4; ++nf) {
        int col = nt * 128 + wc * 64 + nf * 16 + l15;
        size_t idx = ((size_t)b * 325 + row) * 640 + col;
        spo[idx] = acc[mf][nf][r] + SP[idx];
      }
    }
}

// ===== pack spo -> normalized bf16 Spn[b][325][640] =====
__global__ __launch_bounds__(256) void k_pack_sp(
    const float* __restrict__ spo, __hip_bfloat16* __restrict__ Spn) {
  __shared__ float red[4];
  __shared__ float s_inv;
  int node = blockIdx.x;
  const float* row = spo + (size_t)node * 640;
  int t = threadIdx.x;
  float s = 0.f;
  for (int e = t; e < 640; e += 256) { float v = row[e]; s = fmaf(v, v, s); }
  #pragma unroll
  for (int off = 32; off >= 1; off >>= 1) s += __shfl_xor(s, off, 64);
  if ((t & 63) == 0) red[t >> 6] = s;
  __syncthreads();
  if (t == 0) s_inv = 1.f / (sqrtf(red[0] + red[1] + red[2] + red[3]) + EPSN);
  __syncthreads();
  float inv = s_inv;
  for (int e = t; e < 640; e += 256)
    Spn[(size_t)node * 640 + e] = __float2bfloat16(row[e] * inv);
}

// ===== pack qpart -> normalized bf16 Qpb[b][975][640] =====
__global__ __launch_bounds__(256) void k_pack_qp(
    const float* __restrict__ qpart, __hip_bfloat16* __restrict__ Qpb) {
  __shared__ float lds0[8320];
  __shared__ float pinv[13];
  int bq = blockIdx.x;
  const float* src = qpart + (size_t)bq * 8320;
  int t = threadIdx.x;
  #pragma unroll
  for (int i = 0; i < 33; ++i) {
    int e = t + i * 256;
    if (e < 8320) lds0[e] = src[e];
  }
  __syncthreads();
  int g = t >> 4, l = t & 15;
  if (g < 13) {
    float s = 0.f;
    for (int c = l; c < 640; c += 16) { float v = lds0[c * 13 + g]; s = fmaf(v, v, s); }
    #pragma unroll
    for (int off = 8; off >= 1; off >>= 1) s += __shfl_xor(s, off, 16);
    if (l == 0) pinv[g] = 1.f / (sqrtf(s) + EPSN);
  }
  __syncthreads();
  #pragma unroll
  for (int i = 0; i < 33; ++i) {
    int j = t + i * 256;
    if (j < 8320) {
      int p = j / 640, c = j % 640;
      Qpb[((size_t)bq * 13 + p) * 640 + c] = __float2bfloat16(lds0[c * 13 + p] * pinv[p]);
    }
  }
}

// ===== part GEMM: Cpart[b][1024][384] = Qpb x Spn^T =====
__global__ __launch_bounds__(256) void k_part_mfma(
    const __hip_bfloat16* __restrict__ Qpb, const __hip_bfloat16* __restrict__ Spn,
    float* __restrict__ Cpart) {
  __shared__ __align__(16) __bf16 ldsA[128 * 64];
  __shared__ __align__(16) __bf16 ldsB[128 * 64];
  int nt = blockIdx.x, mt = blockIdx.y, b = blockIdx.z;
  int tid = threadIdx.x;
  int w = tid >> 6, lane = tid & 63;
  int l15 = lane & 15, l4 = lane >> 4;
  int wr = w >> 1, wc = w & 1;
  const __hip_bfloat16* A = Qpb + (size_t)b * 975 * 640;
  const __hip_bfloat16* B = Spn + (size_t)b * 325 * 640;
  f32x4 acc[4][4];
  #pragma unroll
  for (int i = 0; i < 4; ++i)
    #pragma unroll
    for (int j = 0; j < 4; ++j) acc[i][j] = (f32x4){0.f, 0.f, 0.f, 0.f};
  for (int kt = 0; kt < 10; ++kt) {
    int c0 = kt * 64;
    __syncthreads();
    stage128(A, 640, mt * 128, 974, c0, ldsA, w, lane);
    stage128(B, 640, nt * 128, 324, c0, ldsB, w, lane);
    __syncthreads();
    compute64(ldsA, ldsB, wr, wc, l15, l4, acc);
  }
  #pragma unroll
  for (int mf = 0; mf < 4; ++mf)
    #pragma unroll
    for (int r = 0; r < 4; ++r) {
      int row = mt * 128 + wr * 64 + mf * 16 + l4 * 4 + r;
      #pragma unroll
      for (int nf = 0; nf < 4; ++nf) {
        int col = nt * 128 + wc * 64 + nf * 16 + l15;
        Cpart[((size_t)b * 1024 + row) * 384 + col] = acc[mf][nf][r];
      }
    }
}

// ===== part reduce =====
__global__ void k_part_reduce(const float* __restrict__ Cpart, float* __restrict__ plog) {
  int w = blockIdx.x * 4 + (threadIdx.x >> 6);
  int lane = threadIdx.x & 63;
  if (w >= 1500) return;
  int bq = w / 5, n = w % 5;
  int b = bq / 75, q = bq % 75;
  int qp = lane >> 2, c4 = lane & 3;
  float m = -1e30f;
  if (qp < 13) {
    const float* row = Cpart + ((size_t)b * 1024 + q * 13 + qp) * 384 + n * 65;
    int hi = c4 * 17 + 17; if (hi > 65) hi = 65;
    for (int cc = c4 * 17; cc < hi; ++cc) m = fmaxf(m, row[cc]);
  }
  m = fmaxf(m, __shfl_xor(m, 1));
  m = fmaxf(m, __shfl_xor(m, 2));
  float contrib = (qp < 13 && c4 == 0) ? m : 0.f;
  #pragma unroll
  for (int off = 32; off >= 1; off >>= 1) contrib += __shfl_xor(contrib, off, 64);
  if (lane == 0) plog[w] = contrib;
}

// ===== pixel GEMM bf16 MFMA, 64x64 wave tiles, fused strip-max =====
__global__ __launch_bounds__(256) void k_pixel_mfma(
    const __hip_bfloat16* __restrict__ Qn, const __hip_bfloat16* __restrict__ Sn,
    const float* __restrict__ qinv, const float* __restrict__ sinv,
    float* __restrict__ pmax) {
  __shared__ __align__(16) __bf16 ldsA[128 * 64];
  __shared__ __align__(16) __bf16 ldsB[128 * 64];
  __shared__ float smax[128][2];
  int x = blockIdx.x;
  int strip = x / 5, n = x % 5;
  int qt = blockIdx.y;
  int b = blockIdx.z;
  int tid = threadIdx.x;
  int w = tid >> 6, lane = tid & 63;
  int l15 = lane & 15, l4 = lane >> 4;
  int wr = w >> 1, wc = w & 1;

  const __hip_bfloat16* QnB = Qn + (size_t)b * 7500 * 640;
  const __hip_bfloat16* SnB = Sn + ((size_t)b * 2500 + n * 500) * 640;

  f32x4 acc[4][4];
  #pragma unroll
  for (int i = 0; i < 4; ++i)
    #pragma unroll
    for (int j = 0; j < 4; ++j) acc[i][j] = (f32x4){0.f, 0.f, 0.f, 0.f};

  for (int kt = 0; kt < 10; ++kt) {
    int c0 = kt * 64;
    __syncthreads();
    stage128(QnB, 640, qt * 128, 7499, c0, ldsA, w, lane);
    stage128(SnB, 640, strip * 128, 499, c0, ldsB, w, lane);
    __syncthreads();
    compute64(ldsA, ldsB, wr, wc, l15, l4, acc);
  }

  int z = b * 5 + n;
  float sscale[4]; bool svalid[4];
  #pragma unroll
  for (int nf = 0; nf < 4; ++nf) {
    int scol = strip * 128 + wc * 64 + nf * 16 + l15;
    svalid[nf] = scol < 500;
    sscale[nf] = sinv[b * 2500 + n * 500 + (svalid[nf] ? scol : 0)];
  }
  #pragma unroll
  for (int mf = 0; mf < 4; ++mf) {
    #pragma unroll
    for (int r = 0; r < 4; ++r) {
      float m = -1e30f;
      #pragma unroll
      for (int nf = 0; nf < 4; ++nf) {
        float v = acc[mf][nf][r] * sscale[nf];
        if (svalid[nf]) m = fmaxf(m, v);
      }
      #pragma unroll
      for (int off = 8; off >= 1; off >>= 1) m = fmaxf(m, __shfl_xor(m, off));
      if (l15 == 0) smax[wr * 64 + mf * 16 + l4 * 4 + r][wc] = m;
    }
  }
  __syncthreads();
  if (tid < 128) {
    int row = qt * 128 + tid;
    if (row < 7500) {
      float m = fmaxf(smax[tid][0], smax[tid][1]);
      pmax[((size_t)z * 7500 + row) * 4 + strip] = m * qinv[b * 7500 + row];
    }
  }
}

// ===== pixel reduce (wave-parallel) =====
__global__ void k_pixel_reduce(const float* __restrict__ pmax, float* __restrict__ pxlog) {
  int t = blockIdx.x * 4 + (threadIdx.x >> 6);
  int lane = threadIdx.x & 63;
  if (t >= 1500) return;
  int r = t / 5, n = t % 5;
  int b = r / 75, q = r % 75;
  const float* base = pmax + (size_t)((b * 5 + n) * 7500 + q * 100) * 4;
  float s = 0.f;
  for (int p = lane; p < 100; p += 64) {
    float4 v = *(const float4*)&base[p * 4];
    s += fmaxf(fmaxf(v.x, v.y), fmaxf(v.z, v.w));
  }
  #pragma unroll
  for (int off = 32; off >= 1; off >>= 1) s += __shfl_xor(s, off, 64);
  if (lane == 0) pxlog[t] = s;
}

// ===== final combine =====
__device__ inline void softmax5_add(const float* l, float wgt, float* acc) {
  float m = fmaxf(fmaxf(fmaxf(l[0], l[1]), fmaxf(l[2], l[3])), l[4]);
  float e[5]; float s = 0.f;
  #pragma unroll
  for (int i = 0; i < 5; ++i) { e[i] = expf(l[i] - m); s += e[i]; }
  float r = wgt / s;
  #pragma unroll
  for (int i = 0; i < 5; ++i) acc[i] += e[i] * r;
}

__global__ void k_combine(const float* __restrict__ plog, const float* __restrict__ pxlog,
                          const float* __restrict__ glog, float* __restrict__ out) {
  int t = blockIdx.x * blockDim.x + threadIdx.x;
  if (t >= 300) return;
  float accv[5] = {0.f, 0.f, 0.f, 0.f, 0.f};
  float l[5];
  #pragma unroll
  for (int i = 0; i < 5; ++i) l[i] = plog[t * 5 + i];
  softmax5_add(l, 1.0f, accv);
  #pragma unroll
  for (int i = 0; i < 5; ++i) l[i] = pxlog[t * 5 + i];
  softmax5_add(l, 0.5f, accv);
  #pragma unroll
  for (int i = 0; i < 5; ++i) l[i] = glog[t * 5 + i];
  softmax5_add(l, 0.5f, accv);
  #pragma unroll
  for (int i = 0; i < 5; ++i) out[t * 5 + i] = accv[i];
}

// ===== launch =====
extern "C" void kernel_launch(void* const* d_in, const int* in_sizes, int n_in,
                              void* d_out, int out_size, void* d_ws, size_t ws_size,
                              hipStream_t stream) {
  (void)in_sizes; (void)n_in; (void)out_size; (void)ws_size;
  const float* support = (const float*)d_in[0];  // [4,25,640,10,10]
  const float* query   = (const float*)d_in[1];  // [4,75,640,10,10]
  const float* spart   = (const float*)d_in[2];  // [4,25,640,13,1]
  const float* qpart   = (const float*)d_in[3];  // [4,75,640,13,1]
  const float* Wq      = (const float*)d_in[4];
  const float* Wk      = (const float*)d_in[5];
  const float* Wv      = (const float*)d_in[6];
  float* out = (float*)d_out;                    // [300,5]
  float* ws = (float*)d_ws;

  size_t o = 0;
  __hip_bfloat16* Qn  = (__hip_bfloat16*)(ws + o); o += 9600000;  // 4*7500*640
  __hip_bfloat16* Sn  = (__hip_bfloat16*)(ws + o); o += 3200000;  // 4*2500*640
  __hip_bfloat16* Qpb = (__hip_bfloat16*)(ws + o); o += 1248000;  // 4*975*640
  __hip_bfloat16* Spn = (__hip_bfloat16*)(ws + o); o += 416000;   // 4*325*640
  __hip_bfloat16* SPa = (__hip_bfloat16*)(ws + o); o += 416000;   // 4*325*640
  __hip_bfloat16* Wt  = (__hip_bfloat16*)(ws + o); o += 614400;   // 3*640*640
  float* qkv_region = ws + o;                       // reused region:
  __hip_bfloat16* Qb16 = (__hip_bfloat16*)(ws + o); o += 416000;  // 4*325*640
  __hip_bfloat16* Kb16 = (__hip_bfloat16*)(ws + o); o += 416000;  // 4*325*640
  __hip_bfloat16* Vt16 = (__hip_bfloat16*)(ws + o); o += 491520;  // 4*640*384
  __hip_bfloat16* attb = (__hip_bfloat16*)(ws + o); o += 249600;  // 4*325*384
  float* qsq   = ws + o; o += 30000;   // becomes qinv in place
  float* ssq   = ws + o; o += 10000;   // becomes sinv in place
  float* qg    = ws + o; o += 192000;
  float* sgap  = ws + o; o += 64000;
  float* SP    = ws + o; o += 832000;
  float* S     = ws + o; o += 422500;
  float* spo   = ws + o; o += 832000;
  float* plog  = ws + o; o += 1500;
  float* pxlog = ws + o; o += 1500;
  float* glog  = ws + o; o += 1500;
  // aliases (lifetimes disjoint, stream-serialized):
  float* Cpart = qkv_region;   // 4*1024*384 = 1,572,864 <= 1,573,120 (Qb16..attb)
  float* pmax  = qkv_region;   // 600,000 (written after Cpart is consumed)
  float* qinv  = qsq;
  float* sinv  = ssq;

  hipMemsetAsync(qsq, 0, 40000 * sizeof(float), stream);  // qsq+ssq contiguous
  k_transpose_bf16<<<dim3(300, 10), 256, 0, stream>>>(query, Qn, qg, qsq);
  k_transpose_bf16<<<dim3(100, 10), 256, 0, stream>>>(support, Sn, sgap, ssq);
  k_finalize_inv<<<157, 256, 0, stream>>>(qsq);
  k_sp_build<<<3250, 256, 0, stream>>>(spart, SP, SPa);
  k_w_pack<<<dim3(100, 3), 256, 0, stream>>>(Wq, Wk, Wv, Wt);
  k_qkv_mfma<<<dim3(5, 3, 12), 256, 0, stream>>>(SPa, Wt, Qb16, Kb16, Vt16);
  k_scores_mfma<<<dim3(3, 3, 4), 256, 0, stream>>>(Qb16, Kb16, S);
  k_softmax_attb<<<325, 256, 0, stream>>>(S, attb);
  k_av_mfma<<<dim3(5, 3, 4), 256, 0, stream>>>(attb, Vt16, SP, spo);
  k_pack_sp<<<1300, 256, 0, stream>>>(spo, Spn);
  k_pack_qp<<<300, 256, 0, stream>>>(qpart, Qpb);
  k_part_mfma<<<dim3(3, 8, 4), 256, 0, stream>>>(Qpb, Spn, Cpart);
  k_part_reduce<<<375, 256, 0, stream>>>(Cpart, plog);
  k_proto_d2<<<20, 256, 0, stream>>>(sgap, qg, glog);
  k_pixel_mfma<<<dim3(20, 59, 4), 256, 0, stream>>>(Qn, Sn, qinv, sinv, pmax);
  k_pixel_reduce<<<375, 256, 0, stream>>>(pmax, pxlog);
  k_combine<<<1, 512, 0, stream>>>(plog, pxlog, glog, out);
}